// Round 5
// baseline (2764.194 us; speedup 1.0000x reference)
//
#include <hip/hip_runtime.h>
#include <hip/hip_bf16.h>

#define SEQ 2305
#define NROWS 4610      // B*SEQ
#define MPAD 4736       // NROWS rounded up to 128
#define DIM 512
#define QKVN 1536
#define NBLK 768        // 3 blocks/CU on 256 CUs -- must all be co-resident

typedef __attribute__((ext_vector_type(8))) short v8s;
typedef __attribute__((ext_vector_type(4))) float v4f;

__device__ __forceinline__ float bf2f(unsigned short u) {
    return __uint_as_float(((unsigned)u) << 16);
}

__device__ __forceinline__ void load_lds16(const void* g, void* l) {
    __builtin_amdgcn_global_load_lds(
        (const __attribute__((address_space(1))) void*)g,
        (__attribute__((address_space(3))) void*)l, 16, 0, 0);
}

struct WPack { const float* p[12]; };

// LDS union across phases: max member 32 KB -> 5 blocks/CU by LDS, 3 by launch_bounds.
union SharedU {
    struct { short As[2][128 * 32]; short Bs[2][128 * 32]; } qk;                      // 32 KB
    struct { short As[2][64 * 32];  short Bs[2][128 * 32]; } wo;                      // 24 KB
    struct { short Ks[64 * 64]; short Vs[64 * 64]; short Ps[64 * 72]; float invl[64]; } ax;
    struct { short Vs[128 * 64]; unsigned short Ps[16 * 264]; float redm[64]; float reds[64]; } nb;
    struct { float tile[32][33]; } pr;
};

// ---- manual grid barrier: all NBLK blocks are co-resident by construction ----
__device__ __forceinline__ void gsync(unsigned* cnt, unsigned* gen) {
    __syncthreads();
    if (threadIdx.x == 0) {
        __threadfence();    // release: agent-scope fence (L2 writeback across XCDs)
        unsigned g = __hip_atomic_load(gen, __ATOMIC_RELAXED, __HIP_MEMORY_SCOPE_AGENT);
        unsigned a = __hip_atomic_fetch_add(cnt, 1u, __ATOMIC_ACQ_REL, __HIP_MEMORY_SCOPE_AGENT);
        if (a == NBLK - 1) {
            __hip_atomic_store(cnt, 0u, __ATOMIC_RELAXED, __HIP_MEMORY_SCOPE_AGENT);
            __hip_atomic_fetch_add(gen, 1u, __ATOMIC_RELEASE, __HIP_MEMORY_SCOPE_AGENT);
        } else {
            while (__hip_atomic_load(gen, __ATOMIC_ACQUIRE, __HIP_MEMORY_SCOPE_AGENT) == g)
                __builtin_amdgcn_s_sleep(8);
        }
        __threadfence();    // acquire: invalidate local L2 before reading producers' data
    }
    __syncthreads();
}

// ---------------- phase: weight transpose + x cast + colsum zero ----------------
__device__ __forceinline__ void phase_prep(SharedU& sm, int tid, int bid, const WPack& wp,
        __hip_bfloat16* wqkv, __hip_bfloat16* wo, const float4* xin,
        __hip_bfloat16* xb, int n4, float* colsum) {
    int tx = tid & 31, ty = tid >> 5;   // (32,8) shape
    for (int j = bid; j < 12 * 256; j += NBLK) {
        int m = j >> 8, r = j & 255;
        int bx = (r & 15) * 32, by = (r >> 4) * 32;
        const float* src = wp.p[m];
        int l = m >> 2, jw = m & 3;
        __hip_bfloat16* dst = (jw < 3) ? (wqkv + (size_t)l * QKVN * DIM + (size_t)jw * DIM * DIM)
                                       : (wo + (size_t)l * DIM * DIM);
        #pragma unroll
        for (int i = 0; i < 4; i++)
            sm.pr.tile[ty + 8 * i][tx] = src[(size_t)(by + ty + 8 * i) * DIM + bx + tx];
        __syncthreads();
        #pragma unroll
        for (int i = 0; i < 4; i++)
            dst[(size_t)(bx + ty + 8 * i) * DIM + by + tx] = __float2bfloat16(sm.pr.tile[tx][ty + 8 * i]);
        __syncthreads();   // tile reused next job
    }
    if (bid == 0) {
        #pragma unroll
        for (int k = 0; k < 4; k++) colsum[k * 256 + tid] = 0.f;
    }
    for (int i = bid * 256 + tid; i < n4; i += NBLK * 256) {
        float4 v = xin[i];
        int j = i * 4;
        xb[j + 0] = __float2bfloat16(v.x);
        xb[j + 1] = __float2bfloat16(v.y);
        xb[j + 2] = __float2bfloat16(v.z);
        xb[j + 3] = __float2bfloat16(v.w);
    }
}

// ---------------- phase: QKV GEMM 128x128 tile, BK=64 (twin 32-k sub-buffers) ----------------
__device__ __forceinline__ void phase_qkv(SharedU& sm, int tid, int job,
        const __hip_bfloat16* A, const __hip_bfloat16* Bt,
        __hip_bfloat16* Cb, float* colsum) {
    const int K = 512, M = NROWS, N = QKVN;
    int wid = tid >> 6, lane = tid & 63;
    int quad = lane >> 4, l16 = lane & 15;
    int bM = (job % 37) * 128, bN = (job / 37) * 128;
    int wM = (wid >> 1) * 64, wN = (wid & 1) * 64;

    const short* Ag = (const short*)A;
    const short* Bg = (const short*)Bt;
    int rowS = wid * 16 + (lane >> 2);
    int kk8 = (lane & 3) * 8;
    const short* gA = Ag + (size_t)(bM + rowS) * K + kk8;
    const short* gB = Bg + (size_t)(bN + rowS) * K + kk8;

    v4f acc[4][4] = {};
    for (int k0 = 0; k0 < K; k0 += 64) {
        #pragma unroll
        for (int s = 0; s < 2; s++) {
            #pragma unroll
            for (int r = 0; r < 2; r++) {
                load_lds16(gA + k0 + s * 32 + (size_t)r * 64 * K, sm.qk.As[s] + r * 2048 + wid * 512);
                load_lds16(gB + k0 + s * 32 + (size_t)r * 64 * K, sm.qk.Bs[s] + r * 2048 + wid * 512);
            }
        }
        __syncthreads();
        #pragma unroll
        for (int s = 0; s < 2; s++) {
            v8s af[4], bf[4];
            #pragma unroll
            for (int i = 0; i < 4; i++)
                af[i] = *(const v8s*)(sm.qk.As[s] + (wM + i * 16 + l16) * 32 + quad * 8);
            #pragma unroll
            for (int j = 0; j < 4; j++)
                bf[j] = *(const v8s*)(sm.qk.Bs[s] + (wN + j * 16 + l16) * 32 + quad * 8);
            #pragma unroll
            for (int i = 0; i < 4; i++)
                #pragma unroll
                for (int j = 0; j < 4; j++)
                    acc[i][j] = __builtin_amdgcn_mfma_f32_16x16x32_bf16(af[i], bf[j], acc[i][j], 0, 0, 0);
        }
        __syncthreads();
    }

    #pragma unroll
    for (int i = 0; i < 4; i++) {
        int row = bM + wM + i * 16 + quad * 4;
        #pragma unroll
        for (int j = 0; j < 4; j++) {
            int col = bN + wN + j * 16 + l16;
            #pragma unroll
            for (int r = 0; r < 4; r++) {
                int rr = row + r;
                if (rr < M)
                    Cb[(size_t)rr * N + col] = __float2bfloat16(acc[i][j][r]);
            }
        }
    }

    if (colsum) {
        #pragma unroll
        for (int j = 0; j < 4; j++) {
            int col = bN + wN + j * 16 + l16;
            if (col >= 1024) {
                float s0 = 0.f, s1 = 0.f;
                #pragma unroll
                for (int i = 0; i < 4; i++) {
                    int row = bM + wM + i * 16 + quad * 4;
                    #pragma unroll
                    for (int r = 0; r < 4; r++) {
                        int rr = row + r;
                        if (rr < M) {
                            float v = acc[i][j][r];
                            if (rr >= SEQ) s1 += v; else s0 += v;
                        }
                    }
                }
                s0 += __shfl_xor(s0, 16); s0 += __shfl_xor(s0, 32);
                s1 += __shfl_xor(s1, 16); s1 += __shfl_xor(s1, 32);
                if (quad == 0) {
                    if (s0 != 0.f) atomicAdd(&colsum[col - 1024], s0);
                    if (s1 != 0.f) atomicAdd(&colsum[512 + col - 1024], s1);
                }
            }
        }
    }
}

// ---------------- phase: Wo GEMM 64x128 tile ----------------
__device__ __forceinline__ void phase_wo(SharedU& sm, int tid, int job,
        const __hip_bfloat16* A, const __hip_bfloat16* Bt,
        float* C, const float* bias, const __hip_bfloat16* resb, __hip_bfloat16* Cb) {
    const int K = 512, M = NROWS, N = DIM;
    int wid = tid >> 6, lane = tid & 63;
    int quad = lane >> 4, l16 = lane & 15;
    int bM = (job % 74) * 64, bN = (job / 74) * 128;
    int wM = (wid >> 1) * 32, wN = (wid & 1) * 64;

    const short* Ag = (const short*)A;
    const short* Bg = (const short*)Bt;
    int rowS = tid >> 2, cg = tid & 3;
    const short* gA = Ag + (size_t)(bM + rowS) * K + cg * 8;
    const short* gB0 = Bg + (size_t)(bN + rowS) * K + cg * 8;
    const short* gB1 = Bg + (size_t)(bN + 64 + rowS) * K + cg * 8;

    v4f acc[2][4] = {};
    for (int k0 = 0; k0 < K; k0 += 64) {
        #pragma unroll
        for (int s = 0; s < 2; s++) {
            load_lds16(gA + k0 + s * 32, sm.wo.As[s] + wid * 512);
            load_lds16(gB0 + k0 + s * 32, sm.wo.Bs[s] + wid * 512);
            load_lds16(gB1 + k0 + s * 32, sm.wo.Bs[s] + 2048 + wid * 512);
        }
        __syncthreads();
        #pragma unroll
        for (int s = 0; s < 2; s++) {
            v8s af[2], bf[4];
            #pragma unroll
            for (int i = 0; i < 2; i++)
                af[i] = *(const v8s*)(sm.wo.As[s] + (wM + i * 16 + l16) * 32 + quad * 8);
            #pragma unroll
            for (int j = 0; j < 4; j++)
                bf[j] = *(const v8s*)(sm.wo.Bs[s] + (wN + j * 16 + l16) * 32 + quad * 8);
            #pragma unroll
            for (int i = 0; i < 2; i++)
                #pragma unroll
                for (int j = 0; j < 4; j++)
                    acc[i][j] = __builtin_amdgcn_mfma_f32_16x16x32_bf16(af[i], bf[j], acc[i][j], 0, 0, 0);
        }
        __syncthreads();
    }

    const unsigned short* resu = (const unsigned short*)resb;
    #pragma unroll
    for (int i = 0; i < 2; i++) {
        int row = bM + wM + i * 16 + quad * 4;
        #pragma unroll
        for (int j = 0; j < 4; j++) {
            int col = bN + wN + j * 16 + l16;
            #pragma unroll
            for (int r = 0; r < 4; r++) {
                int rr = row + r;
                if (rr < M) {
                    float v = acc[i][j][r];
                    if (bias) v += bias[col];
                    size_t idx = (size_t)rr * N + col;
                    if (resu) v += bf2f(resu[idx]);
                    if (C) C[idx] = v;
                    if (Cb) Cb[idx] = __float2bfloat16(v);
                }
            }
        }
    }
}

// ---------------- phase: axial attention (one job per block) ----------------
__device__ __forceinline__ void phase_axial(SharedU& sm, int tid, int job,
        const unsigned short* qkvb, __hip_bfloat16* attn_b, int typ) {
    int wid = tid >> 6, lane = tid & 63;
    int quad = lane >> 4, l16 = lane & 15;
    int n = job % 48;
    int byy = job / 48;
    int b = byy >> 3, h = byy & 7;
    size_t rowbase = (size_t)b * SEQ;
    int hoff = h * 64;

    #pragma unroll
    for (int it = 0; it < 2; it++) {
        int linear = it * 256 + tid;
        int slot = linear >> 3;
        int cd = linear & 7;
        int cs = cd ^ (slot & 7);
        int sp = (slot == 0) ? 0
               : (slot <= 48 ? (typ == 0 ? 1 + n * 48 + (slot - 1) : 1 + (slot - 1) * 48 + n) : 0);
        const unsigned short* srcK = qkvb + (rowbase + sp) * QKVN + hoff + 512 + cs * 8;
        load_lds16(srcK, sm.ax.Ks + it * 2048 + wid * 512 + lane * 8);
        const unsigned short* srcV = qkvb + (rowbase + sp) * QKVN + hoff + 1024 + cd * 8;
        load_lds16(srcV, sm.ax.Vs + it * 2048 + wid * 512 + lane * 8);
    }

    int qi = wid * 16 + l16;
    int sp_q = (qi >= 1 && qi <= 48)
             ? (typ == 0 ? 1 + n * 48 + (qi - 1) : 1 + (qi - 1) * 48 + n) : 0;
    const unsigned short* qptr = qkvb + (rowbase + sp_q) * QKVN + hoff + quad * 8;
    v8s qa0 = *(const v8s*)qptr;
    v8s qa1 = *(const v8s*)(qptr + 32);

    __syncthreads();

    if (n == 0 && tid < 64) {
        attn_b[rowbase * DIM + hoff + tid] =
            __float2bfloat16(bf2f(qkvb[rowbase * QKVN + hoff + 1024 + tid]));
    }

    v4f st[4];
    #pragma unroll
    for (int kt = 0; kt < 4; kt++) {
        int slot = kt * 16 + l16;
        int s7 = slot & 7;
        v8s blo = *(const v8s*)(sm.ax.Ks + slot * 64 + ((quad ^ s7) * 8));
        v8s bhi = *(const v8s*)(sm.ax.Ks + slot * 64 + (((4 + quad) ^ s7) * 8));
        v4f a = {};
        a = __builtin_amdgcn_mfma_f32_16x16x32_bf16(qa0, blo, a, 0, 0, 0);
        a = __builtin_amdgcn_mfma_f32_16x16x32_bf16(qa1, bhi, a, 0, 0, 0);
        st[kt] = a;
    }

    const float NEG = -3.0e38f;
    float sv[4][4];
    float pm[4] = {NEG, NEG, NEG, NEG};
    #pragma unroll
    for (int kt = 0; kt < 4; kt++) {
        int j = kt * 16 + l16;
        #pragma unroll
        for (int r = 0; r < 4; r++) {
            int i = wid * 16 + quad * 4 + r;
            bool ok = (i >= 1) && (i <= 48) && (j <= i);
            float v = ok ? st[kt][r] * 0.125f : NEG;
            sv[kt][r] = v;
            pm[r] = fmaxf(pm[r], v);
        }
    }
    #pragma unroll
    for (int r = 0; r < 4; r++)
        for (int o = 1; o < 16; o <<= 1) pm[r] = fmaxf(pm[r], __shfl_xor(pm[r], o));

    float ps[4] = {0.f, 0.f, 0.f, 0.f};
    #pragma unroll
    for (int kt = 0; kt < 4; kt++) {
        int j = kt * 16 + l16;
        #pragma unroll
        for (int r = 0; r < 4; r++) {
            float e = __expf(sv[kt][r] - pm[r]);
            ps[r] += e;
            sm.ax.Ps[(wid * 16 + quad * 4 + r) * 72 + j] = (short)__bfloat16_as_ushort(__float2bfloat16(e));
        }
    }
    #pragma unroll
    for (int r = 0; r < 4; r++)
        for (int o = 1; o < 16; o <<= 1) ps[r] += __shfl_xor(ps[r], o);
    if (l16 == 0) {
        #pragma unroll
        for (int r = 0; r < 4; r++)
            sm.ax.invl[wid * 16 + quad * 4 + r] = 1.0f / ps[r];
    }
    __syncthreads();

    #pragma unroll
    for (int qt = 0; qt < 4; qt++) {
        v4f oc = {};
        #pragma unroll
        for (int kc = 0; kc < 2; kc++) {
            v8s pa = *(const v8s*)(sm.ax.Ps + (qt * 16 + l16) * 72 + kc * 32 + quad * 8);
            v8s bfr;
            #pragma unroll
            for (int jj = 0; jj < 8; jj++)
                bfr[jj] = sm.ax.Vs[(kc * 32 + quad * 8 + jj) * 64 + wid * 16 + l16];
            oc = __builtin_amdgcn_mfma_f32_16x16x32_bf16(pa, bfr, oc, 0, 0, 0);
        }
        #pragma unroll
        for (int r = 0; r < 4; r++) {
            int i = qt * 16 + quad * 4 + r;
            if (i >= 1 && i <= 48) {
                int sp = typ == 0 ? 1 + n * 48 + (i - 1) : 1 + (i - 1) * 48 + n;
                attn_b[(rowbase + sp) * DIM + hoff + wid * 16 + l16] =
                    __float2bfloat16(oc[r] * sm.ax.invl[i]);
            }
        }
    }
}

// ---------------- phase: nearby attention (job-strided) ----------------
__device__ __forceinline__ void phase_nearby(SharedU& sm, int tid, int idx,
        const unsigned short* qkvb, const float* colsum, __hip_bfloat16* attn_b) {
    int wid = tid >> 6, lane = tid & 63;
    int quad = lane >> 4, l16 = lane & 15;

    if (idx >= 2304) {
        int b = idx - 2304;
        size_t rb = (size_t)b * SEQ;
        for (int c = tid; c < 512; c += 256) {
            attn_b[(rb + 2304) * DIM + c] =
                __float2bfloat16(colsum[b * 512 + c] * (1.0f / 2305.0f));
            attn_b[rb * DIM + c] =
                __float2bfloat16(bf2f(qkvb[rb * QKVN + 1024 + c]));
        }
        return;
    }

    int bh = idx & 15;
    int tile = idx >> 4;
    int b = bh >> 3, h = bh & 7;
    int t = tile >> 4;
    int sxy = tile & 15;
    int hh0 = (sxy >> 2) * 4, ww0 = (sxy & 3) * 4;
    int nf = (t < 3 ? t : 3) + 1;
    int t0 = t - (nf - 1);
    size_t rowbase = (size_t)b * SEQ;
    int hoff = h * 64;

    auto slot_kp = [&](int slot) -> int {
        int f = slot >> 6, uy = (slot >> 3) & 7, ux = slot & 7;
        int kh = hh0 - 2 + uy, kw = ww0 - 2 + ux;
        int kt = t0 + f;
        bool ok = (kh >= 0) && (kh < 16) && (kw >= 0) && (kw < 16) && (f < nf);
        return ok ? (kt * 256 + kh * 16 + kw + 1) : 0;
    };

    int qp_f = t * 256 + (hh0 + (l16 >> 2)) * 16 + (ww0 + (l16 & 3));
    const unsigned short* qptr = qkvb + (rowbase + qp_f) * QKVN + hoff + quad * 8;
    v8s qa0 = *(const v8s*)qptr;
    v8s qa1 = *(const v8s*)(qptr + 32);

    v8s kb_lo[4], kb_hi[4];
    #pragma unroll
    for (int k = 0; k < 4; k++) {
        int slot = (wid * 4 + k) * 16 + l16;
        int kp = slot_kp(slot);
        const unsigned short* kr = qkvb + (rowbase + kp) * QKVN + hoff + 512;
        kb_lo[k] = *(const v8s*)(kr + quad * 8);
        kb_hi[k] = *(const v8s*)(kr + 32 + quad * 8);
    }

    #pragma unroll
    for (int it = 0; it < 4; it++) {
        int linear = it * 256 + tid;
        int slot = linear >> 3;
        int cd = linear & 7;
        int cs = cd ^ ((slot >> 3) & 7);
        int kp = slot_kp(slot);
        const unsigned short* src = qkvb + (rowbase + kp) * QKVN + hoff + 1024 + cs * 8;
        load_lds16(src, sm.nb.Vs + it * 2048 + wid * 512 + lane * 8);
    }

    v4f st[4];
    #pragma unroll
    for (int k = 0; k < 4; k++) {
        v4f a = {};
        a = __builtin_amdgcn_mfma_f32_16x16x32_bf16(qa0, kb_lo[k], a, 0, 0, 0);
        a = __builtin_amdgcn_mfma_f32_16x16x32_bf16(qa1, kb_hi[k], a, 0, 0, 0);
        st[k] = a;
    }

    const float NEG = -3.0e38f;
    float sv[4][4];
    float pm[4] = {NEG, NEG, NEG, NEG};
    #pragma unroll
    for (int k = 0; k < 4; k++) {
        int slot = (wid * 4 + k) * 16 + l16;
        int f = slot >> 6, uy = (slot >> 3) & 7, ux = slot & 7;
        int kh = hh0 - 2 + uy, kw = ww0 - 2 + ux;
        bool okb = (kh >= 0) && (kh < 16) && (kw >= 0) && (kw < 16) && (f < nf);
        int dyp2 = uy - quad;
        bool oky = okb && (dyp2 >= 0) && (dyp2 <= 4);
        #pragma unroll
        for (int r = 0; r < 4; r++) {
            int dxp2 = ux - r;
            bool ok = oky && (dxp2 >= 0) && (dxp2 <= 4);
            if (f == nf - 1) ok = ok && (dyp2 * 5 + dxp2 < 12);
            float v = ok ? st[k][r] * 0.125f : NEG;
            sv[k][r] = v;
            pm[r] = fmaxf(pm[r], v);
        }
    }
    #pragma unroll
    for (int r = 0; r < 4; r++)
        for (int o = 1; o < 16; o <<= 1) pm[r] = fmaxf(pm[r], __shfl_xor(pm[r], o));
    if (l16 == 0) {
        #pragma unroll
        for (int r = 0; r < 4; r++) sm.nb.redm[(quad * 4 + r) * 4 + wid] = pm[r];
    }
    __syncthreads();   // barrier 1: redm visible, V half-0 staged

    float rm[4];
    #pragma unroll
    for (int r = 0; r < 4; r++) {
        int row = (quad * 4 + r) * 4;
        rm[r] = fmaxf(fmaxf(sm.nb.redm[row], sm.nb.redm[row + 1]),
                      fmaxf(sm.nb.redm[row + 2], sm.nb.redm[row + 3]));
    }

    float ps[4] = {0.f, 0.f, 0.f, 0.f};
    #pragma unroll
    for (int k = 0; k < 4; k++) {
        int slot = (wid * 4 + k) * 16 + l16;
        #pragma unroll
        for (int r = 0; r < 4; r++) {
            float e = __expf(sv[k][r] - rm[r]);
            ps[r] += e;
            sm.nb.Ps[(quad * 4 + r) * 264 + slot] = __bfloat16_as_ushort(__float2bfloat16(e));
        }
    }
    #pragma unroll
    for (int r = 0; r < 4; r++)
        for (int o = 1; o < 16; o <<= 1) ps[r] += __shfl_xor(ps[r], o);
    if (l16 == 0) {
        #pragma unroll
        for (int r = 0; r < 4; r++) sm.nb.reds[(quad * 4 + r) * 4 + wid] = ps[r];
    }
    __syncthreads();   // barrier 2: Ps + reds visible

    float inv[4];
    #pragma unroll
    for (int r = 0; r < 4; r++) {
        int row = (quad * 4 + r) * 4;
        float d = sm.nb.reds[row] + sm.nb.reds[row + 1] + sm.nb.reds[row + 2] + sm.nb.reds[row + 3];
        inv[r] = 1.0f / d;
    }

    int dcol = wid * 16 + l16;
    int c_r = dcol >> 3, d7 = dcol & 7;
    v4f oc = {};
    #pragma unroll
    for (int kc = 0; kc < 4; kc++) {
        v8s pa = *(const v8s*)((const short*)sm.nb.Ps + l16 * 264 + kc * 32 + quad * 8);
        v8s bf;
        #pragma unroll
        for (int j = 0; j < 8; j++) {
            int slot = kc * 32 + quad * 8 + j;
            int key = (slot >> 3) & 7;
            bf[j] = sm.nb.Vs[(slot & 127) * 64 + ((c_r ^ key) * 8) + d7];
        }
        oc = __builtin_amdgcn_mfma_f32_16x16x32_bf16(pa, bf, oc, 0, 0, 0);
    }
    __syncthreads();   // barrier 3: half-0 reads done

    #pragma unroll
    for (int it = 0; it < 4; it++) {
        int linear = 1024 + it * 256 + tid;
        int slot = linear >> 3;
        int cd = linear & 7;
        int cs = cd ^ ((slot >> 3) & 7);
        int kp = slot_kp(slot);
        const unsigned short* src = qkvb + (rowbase + kp) * QKVN + hoff + 1024 + cs * 8;
        load_lds16(src, sm.nb.Vs + it * 2048 + wid * 512 + lane * 8);
    }
    __syncthreads();   // barrier 4: half-1 staged

    #pragma unroll
    for (int kc = 4; kc < 8; kc++) {
        v8s pa = *(const v8s*)((const short*)sm.nb.Ps + l16 * 264 + kc * 32 + quad * 8);
        v8s bf;
        #pragma unroll
        for (int j = 0; j < 8; j++) {
            int slot = kc * 32 + quad * 8 + j;
            int key = (slot >> 3) & 7;
            bf[j] = sm.nb.Vs[(slot & 127) * 64 + ((c_r ^ key) * 8) + d7];
        }
        oc = __builtin_amdgcn_mfma_f32_16x16x32_bf16(pa, bf, oc, 0, 0, 0);
    }

    #pragma unroll
    for (int r = 0; r < 4; r++) {
        int qp = t * 256 + (hh0 + quad) * 16 + (ww0 + r);
        if (qp != 0) {
            attn_b[(rowbase + qp) * DIM + hoff + dcol] =
                __float2bfloat16(oc[r] * inv[r]);
        }
    }
}

// ---------------- the mega-kernel: whole pipeline, one dispatch ----------------
__global__ __launch_bounds__(256, 3) void mega(
    WPack wp, __hip_bfloat16* __restrict__ wqkv, __hip_bfloat16* __restrict__ wo,
    const float4* __restrict__ xin, __hip_bfloat16* __restrict__ xb,
    __hip_bfloat16* __restrict__ attnb, float* __restrict__ colsum,
    __hip_bfloat16* __restrict__ qkvb, float* __restrict__ xout,
    const float* __restrict__ bo0, const float* __restrict__ bo1, const float* __restrict__ bo2,
    int n4, unsigned* bar_cnt, unsigned* bar_gen) {
    __shared__ SharedU sm;
    int tid = threadIdx.x, bid = blockIdx.x;

    phase_prep(sm, tid, bid, wp, wqkv, wo, xin, xb, n4, colsum);
    gsync(bar_cnt, bar_gen);

    for (int l = 0; l < 3; l++) {
        if (bid < 444)
            phase_qkv(sm, tid, bid, xb, wqkv + (size_t)l * QKVN * DIM, qkvb,
                      (l == 2) ? colsum : nullptr);
        gsync(bar_cnt, bar_gen);

        if (l < 2) {
            phase_axial(sm, tid, bid, (const unsigned short*)qkvb, attnb, l);
        } else {
            for (int j = bid; j < 2306; j += NBLK) {
                phase_nearby(sm, tid, j, (const unsigned short*)qkvb, colsum, attnb);
                __syncthreads();   // protect Vs/Ps before next job's staging
            }
        }
        gsync(bar_cnt, bar_gen);

        const float* bo = (l == 0) ? bo0 : (l == 1) ? bo1 : bo2;
        if (bid < 296) {
            if (l < 2)
                phase_wo(sm, tid, bid, attnb, wo + (size_t)l * DIM * DIM, nullptr, bo, xb, xb);
            else
                phase_wo(sm, tid, bid, attnb, wo + (size_t)l * DIM * DIM, xout, bo, xb, nullptr);
        }
        if (l < 2) gsync(bar_cnt, bar_gen);
    }
}

// ---------------- host launch ----------------
extern "C" void kernel_launch(void* const* d_in, const int* in_sizes, int n_in,
                              void* d_out, int out_size, void* d_ws, size_t ws_size,
                              hipStream_t stream) {
    const float* x = (const float*)d_in[0];
    float* xcur = (float*)d_out;

    char* ws = (char*)d_ws;
    size_t off = 0;
    auto alloc = [&](size_t bytes) -> void* {
        void* p = ws + off;
        off = (off + bytes + 255) & ~(size_t)255;
        return p;
    };
    __hip_bfloat16* wqkv  = (__hip_bfloat16*)alloc((size_t)3 * QKVN * DIM * 2);
    __hip_bfloat16* wo    = (__hip_bfloat16*)alloc((size_t)3 * DIM * DIM * 2);
    __hip_bfloat16* xb    = (__hip_bfloat16*)alloc((size_t)MPAD * DIM * 2);
    __hip_bfloat16* attnb = (__hip_bfloat16*)alloc((size_t)MPAD * DIM * 2);
    float* colsum         = (float*)alloc((size_t)2 * 512 * 4);
    unsigned* bar         = (unsigned*)alloc(256);
    __hip_bfloat16* qkvb  = (__hip_bfloat16*)alloc((size_t)NROWS * QKVN * 2);

    const int n4 = NROWS * DIM / 4;

    WPack wp;
    for (int l = 0; l < 3; l++)
        for (int j = 0; j < 4; j++)
            wp.p[l * 4 + j] = (const float*)d_in[2 + l * 5 + j];

    hipMemsetAsync(bar, 0, 16, stream);   // zero barrier counter + generation

    mega<<<NBLK, 256, 0, stream>>>(
        wp, wqkv, wo, (const float4*)x, xb, attnb, colsum, qkvb, xcur,
        (const float*)d_in[6], (const float*)d_in[11], (const float*)d_in[16],
        n4, bar, bar + 1);
}

// Round 6
// 921.184 us; speedup vs baseline: 3.0007x; 3.0007x over previous
//
#include <hip/hip_runtime.h>
#include <hip/hip_bf16.h>

#define SEQ 2305
#define NROWS 4610      // B*SEQ
#define MPAD 4736       // NROWS rounded up to 128
#define DIM 512
#define QKVN 1536
#define NBLK 512        // 2 blocks/CU on 256 CUs -- comfortable co-residency slack

typedef __attribute__((ext_vector_type(8))) short v8s;
typedef __attribute__((ext_vector_type(4))) float v4f;

__device__ __forceinline__ float bf2f(unsigned short u) {
    return __uint_as_float(((unsigned)u) << 16);
}

__device__ __forceinline__ void load_lds16(const void* g, void* l) {
    __builtin_amdgcn_global_load_lds(
        (const __attribute__((address_space(1))) void*)g,
        (__attribute__((address_space(3))) void*)l, 16, 0, 0);
}

struct WPack { const float* p[12]; };

// LDS union across phases: max member 32 KB -> 2 blocks/CU uses 64/160 KB.
union SharedU {
    struct { short As[2][128 * 32]; short Bs[2][128 * 32]; } qk;                      // 32 KB
    struct { short As[2][64 * 32];  short Bs[2][128 * 32]; } wo;                      // 24 KB
    struct { short Ks[64 * 64]; short Vs[64 * 64]; short Ps[64 * 72]; float invl[64]; } ax;
    struct { short Vs[128 * 64]; unsigned short Ps[16 * 264]; float redm[64]; float reds[64]; } nb;
    struct { float tile[32][33]; } pr;
};

// ---- grid barrier: generation scheme, RELAXED spin + one fence each side ----
__device__ __forceinline__ void gsync(unsigned* cnt, unsigned* gen) {
    __syncthreads();
    if (threadIdx.x == 0) {
        __threadfence();    // release: make this block's global writes visible (L2 wb)
        unsigned g = __hip_atomic_load(gen, __ATOMIC_RELAXED, __HIP_MEMORY_SCOPE_AGENT);
        unsigned a = __hip_atomic_fetch_add(cnt, 1u, __ATOMIC_RELAXED, __HIP_MEMORY_SCOPE_AGENT);
        if (a == NBLK - 1) {
            __hip_atomic_store(cnt, 0u, __ATOMIC_RELAXED, __HIP_MEMORY_SCOPE_AGENT);
            __hip_atomic_fetch_add(gen, 1u, __ATOMIC_RELEASE, __HIP_MEMORY_SCOPE_AGENT);
        } else {
            while (__hip_atomic_load(gen, __ATOMIC_RELAXED, __HIP_MEMORY_SCOPE_AGENT) == g)
                __builtin_amdgcn_s_sleep(16);
        }
        __threadfence();    // acquire: invalidate stale lines before reading producers' data
    }
    __syncthreads();
}

// ---------------- phase: weight transpose + x cast + colsum zero ----------------
__device__ __forceinline__ void phase_prep(SharedU& sm, int tid, int bid, const WPack& wp,
        __hip_bfloat16* wqkv, __hip_bfloat16* wo, const float4* xin,
        __hip_bfloat16* xb, int n4, float* colsum) {
    int tx = tid & 31, ty = tid >> 5;   // (32,8) shape
    for (int j = bid; j < 12 * 256; j += NBLK) {
        int m = j >> 8, r = j & 255;
        int bx = (r & 15) * 32, by = (r >> 4) * 32;
        const float* src = wp.p[m];
        int l = m >> 2, jw = m & 3;
        __hip_bfloat16* dst = (jw < 3) ? (wqkv + (size_t)l * QKVN * DIM + (size_t)jw * DIM * DIM)
                                       : (wo + (size_t)l * DIM * DIM);
        #pragma unroll
        for (int i = 0; i < 4; i++)
            sm.pr.tile[ty + 8 * i][tx] = src[(size_t)(by + ty + 8 * i) * DIM + bx + tx];
        __syncthreads();
        #pragma unroll
        for (int i = 0; i < 4; i++)
            dst[(size_t)(bx + ty + 8 * i) * DIM + by + tx] = __float2bfloat16(sm.pr.tile[tx][ty + 8 * i]);
        __syncthreads();   // tile reused next job
    }
    if (bid == 0) {
        #pragma unroll
        for (int k = 0; k < 4; k++) colsum[k * 256 + tid] = 0.f;
    }
    for (int i = bid * 256 + tid; i < n4; i += NBLK * 256) {
        float4 v = xin[i];
        int j = i * 4;
        xb[j + 0] = __float2bfloat16(v.x);
        xb[j + 1] = __float2bfloat16(v.y);
        xb[j + 2] = __float2bfloat16(v.z);
        xb[j + 3] = __float2bfloat16(v.w);
    }
}

// ---------------- phase: QKV GEMM 128x128 tile, BK=64 (twin 32-k sub-buffers) ----------------
__device__ __forceinline__ void phase_qkv(SharedU& sm, int tid, int job,
        const __hip_bfloat16* A, const __hip_bfloat16* Bt,
        __hip_bfloat16* Cb, float* colsum) {
    const int K = 512, M = NROWS, N = QKVN;
    int wid = tid >> 6, lane = tid & 63;
    int quad = lane >> 4, l16 = lane & 15;
    int bM = (job % 37) * 128, bN = (job / 37) * 128;
    int wM = (wid >> 1) * 64, wN = (wid & 1) * 64;

    const short* Ag = (const short*)A;
    const short* Bg = (const short*)Bt;
    int rowS = wid * 16 + (lane >> 2);
    int kk8 = (lane & 3) * 8;
    const short* gA = Ag + (size_t)(bM + rowS) * K + kk8;
    const short* gB = Bg + (size_t)(bN + rowS) * K + kk8;

    v4f acc[4][4] = {};
    for (int k0 = 0; k0 < K; k0 += 64) {
        #pragma unroll
        for (int s = 0; s < 2; s++) {
            #pragma unroll
            for (int r = 0; r < 2; r++) {
                load_lds16(gA + k0 + s * 32 + (size_t)r * 64 * K, sm.qk.As[s] + r * 2048 + wid * 512);
                load_lds16(gB + k0 + s * 32 + (size_t)r * 64 * K, sm.qk.Bs[s] + r * 2048 + wid * 512);
            }
        }
        __syncthreads();
        #pragma unroll
        for (int s = 0; s < 2; s++) {
            v8s af[4], bf[4];
            #pragma unroll
            for (int i = 0; i < 4; i++)
                af[i] = *(const v8s*)(sm.qk.As[s] + (wM + i * 16 + l16) * 32 + quad * 8);
            #pragma unroll
            for (int j = 0; j < 4; j++)
                bf[j] = *(const v8s*)(sm.qk.Bs[s] + (wN + j * 16 + l16) * 32 + quad * 8);
            #pragma unroll
            for (int i = 0; i < 4; i++)
                #pragma unroll
                for (int j = 0; j < 4; j++)
                    acc[i][j] = __builtin_amdgcn_mfma_f32_16x16x32_bf16(af[i], bf[j], acc[i][j], 0, 0, 0);
        }
        __syncthreads();
    }

    #pragma unroll
    for (int i = 0; i < 4; i++) {
        int row = bM + wM + i * 16 + quad * 4;
        #pragma unroll
        for (int j = 0; j < 4; j++) {
            int col = bN + wN + j * 16 + l16;
            #pragma unroll
            for (int r = 0; r < 4; r++) {
                int rr = row + r;
                if (rr < M)
                    Cb[(size_t)rr * N + col] = __float2bfloat16(acc[i][j][r]);
            }
        }
    }

    if (colsum) {
        #pragma unroll
        for (int j = 0; j < 4; j++) {
            int col = bN + wN + j * 16 + l16;
            if (col >= 1024) {
                float s0 = 0.f, s1 = 0.f;
                #pragma unroll
                for (int i = 0; i < 4; i++) {
                    int row = bM + wM + i * 16 + quad * 4;
                    #pragma unroll
                    for (int r = 0; r < 4; r++) {
                        int rr = row + r;
                        if (rr < M) {
                            float v = acc[i][j][r];
                            if (rr >= SEQ) s1 += v; else s0 += v;
                        }
                    }
                }
                s0 += __shfl_xor(s0, 16); s0 += __shfl_xor(s0, 32);
                s1 += __shfl_xor(s1, 16); s1 += __shfl_xor(s1, 32);
                if (quad == 0) {
                    if (s0 != 0.f) atomicAdd(&colsum[col - 1024], s0);
                    if (s1 != 0.f) atomicAdd(&colsum[512 + col - 1024], s1);
                }
            }
        }
    }
}

// ---------------- phase: Wo GEMM 64x128 tile ----------------
__device__ __forceinline__ void phase_wo(SharedU& sm, int tid, int job,
        const __hip_bfloat16* A, const __hip_bfloat16* Bt,
        float* C, const float* bias, const __hip_bfloat16* resb, __hip_bfloat16* Cb) {
    const int K = 512, M = NROWS, N = DIM;
    int wid = tid >> 6, lane = tid & 63;
    int quad = lane >> 4, l16 = lane & 15;
    int bM = (job % 74) * 64, bN = (job / 74) * 128;
    int wM = (wid >> 1) * 32, wN = (wid & 1) * 64;

    const short* Ag = (const short*)A;
    const short* Bg = (const short*)Bt;
    int rowS = tid >> 2, cg = tid & 3;
    const short* gA = Ag + (size_t)(bM + rowS) * K + cg * 8;
    const short* gB0 = Bg + (size_t)(bN + rowS) * K + cg * 8;
    const short* gB1 = Bg + (size_t)(bN + 64 + rowS) * K + cg * 8;

    v4f acc[2][4] = {};
    for (int k0 = 0; k0 < K; k0 += 64) {
        #pragma unroll
        for (int s = 0; s < 2; s++) {
            load_lds16(gA + k0 + s * 32, sm.wo.As[s] + wid * 512);
            load_lds16(gB0 + k0 + s * 32, sm.wo.Bs[s] + wid * 512);
            load_lds16(gB1 + k0 + s * 32, sm.wo.Bs[s] + 2048 + wid * 512);
        }
        __syncthreads();
        #pragma unroll
        for (int s = 0; s < 2; s++) {
            v8s af[2], bf[4];
            #pragma unroll
            for (int i = 0; i < 2; i++)
                af[i] = *(const v8s*)(sm.wo.As[s] + (wM + i * 16 + l16) * 32 + quad * 8);
            #pragma unroll
            for (int j = 0; j < 4; j++)
                bf[j] = *(const v8s*)(sm.wo.Bs[s] + (wN + j * 16 + l16) * 32 + quad * 8);
            #pragma unroll
            for (int i = 0; i < 2; i++)
                #pragma unroll
                for (int j = 0; j < 4; j++)
                    acc[i][j] = __builtin_amdgcn_mfma_f32_16x16x32_bf16(af[i], bf[j], acc[i][j], 0, 0, 0);
        }
        __syncthreads();
    }

    const unsigned short* resu = (const unsigned short*)resb;
    #pragma unroll
    for (int i = 0; i < 2; i++) {
        int row = bM + wM + i * 16 + quad * 4;
        #pragma unroll
        for (int j = 0; j < 4; j++) {
            int col = bN + wN + j * 16 + l16;
            #pragma unroll
            for (int r = 0; r < 4; r++) {
                int rr = row + r;
                if (rr < M) {
                    float v = acc[i][j][r];
                    if (bias) v += bias[col];
                    size_t idx = (size_t)rr * N + col;
                    if (resu) v += bf2f(resu[idx]);
                    if (C) C[idx] = v;
                    if (Cb) Cb[idx] = __float2bfloat16(v);
                }
            }
        }
    }
}

// ---------------- phase: axial attention (job-strided) ----------------
__device__ __forceinline__ void phase_axial(SharedU& sm, int tid, int job,
        const unsigned short* qkvb, __hip_bfloat16* attn_b, int typ) {
    int wid = tid >> 6, lane = tid & 63;
    int quad = lane >> 4, l16 = lane & 15;
    int n = job % 48;
    int byy = job / 48;
    int b = byy >> 3, h = byy & 7;
    size_t rowbase = (size_t)b * SEQ;
    int hoff = h * 64;

    #pragma unroll
    for (int it = 0; it < 2; it++) {
        int linear = it * 256 + tid;
        int slot = linear >> 3;
        int cd = linear & 7;
        int cs = cd ^ (slot & 7);
        int sp = (slot == 0) ? 0
               : (slot <= 48 ? (typ == 0 ? 1 + n * 48 + (slot - 1) : 1 + (slot - 1) * 48 + n) : 0);
        const unsigned short* srcK = qkvb + (rowbase + sp) * QKVN + hoff + 512 + cs * 8;
        load_lds16(srcK, sm.ax.Ks + it * 2048 + wid * 512 + lane * 8);
        const unsigned short* srcV = qkvb + (rowbase + sp) * QKVN + hoff + 1024 + cd * 8;
        load_lds16(srcV, sm.ax.Vs + it * 2048 + wid * 512 + lane * 8);
    }

    int qi = wid * 16 + l16;
    int sp_q = (qi >= 1 && qi <= 48)
             ? (typ == 0 ? 1 + n * 48 + (qi - 1) : 1 + (qi - 1) * 48 + n) : 0;
    const unsigned short* qptr = qkvb + (rowbase + sp_q) * QKVN + hoff + quad * 8;
    v8s qa0 = *(const v8s*)qptr;
    v8s qa1 = *(const v8s*)(qptr + 32);

    __syncthreads();

    if (n == 0 && tid < 64) {
        attn_b[rowbase * DIM + hoff + tid] =
            __float2bfloat16(bf2f(qkvb[rowbase * QKVN + hoff + 1024 + tid]));
    }

    v4f st[4];
    #pragma unroll
    for (int kt = 0; kt < 4; kt++) {
        int slot = kt * 16 + l16;
        int s7 = slot & 7;
        v8s blo = *(const v8s*)(sm.ax.Ks + slot * 64 + ((quad ^ s7) * 8));
        v8s bhi = *(const v8s*)(sm.ax.Ks + slot * 64 + (((4 + quad) ^ s7) * 8));
        v4f a = {};
        a = __builtin_amdgcn_mfma_f32_16x16x32_bf16(qa0, blo, a, 0, 0, 0);
        a = __builtin_amdgcn_mfma_f32_16x16x32_bf16(qa1, bhi, a, 0, 0, 0);
        st[kt] = a;
    }

    const float NEG = -3.0e38f;
    float sv[4][4];
    float pm[4] = {NEG, NEG, NEG, NEG};
    #pragma unroll
    for (int kt = 0; kt < 4; kt++) {
        int j = kt * 16 + l16;
        #pragma unroll
        for (int r = 0; r < 4; r++) {
            int i = wid * 16 + quad * 4 + r;
            bool ok = (i >= 1) && (i <= 48) && (j <= i);
            float v = ok ? st[kt][r] * 0.125f : NEG;
            sv[kt][r] = v;
            pm[r] = fmaxf(pm[r], v);
        }
    }
    #pragma unroll
    for (int r = 0; r < 4; r++)
        for (int o = 1; o < 16; o <<= 1) pm[r] = fmaxf(pm[r], __shfl_xor(pm[r], o));

    float ps[4] = {0.f, 0.f, 0.f, 0.f};
    #pragma unroll
    for (int kt = 0; kt < 4; kt++) {
        int j = kt * 16 + l16;
        #pragma unroll
        for (int r = 0; r < 4; r++) {
            float e = __expf(sv[kt][r] - pm[r]);
            ps[r] += e;
            sm.ax.Ps[(wid * 16 + quad * 4 + r) * 72 + j] = (short)__bfloat16_as_ushort(__float2bfloat16(e));
        }
    }
    #pragma unroll
    for (int r = 0; r < 4; r++)
        for (int o = 1; o < 16; o <<= 1) ps[r] += __shfl_xor(ps[r], o);
    if (l16 == 0) {
        #pragma unroll
        for (int r = 0; r < 4; r++)
            sm.ax.invl[wid * 16 + quad * 4 + r] = 1.0f / ps[r];
    }
    __syncthreads();

    #pragma unroll
    for (int qt = 0; qt < 4; qt++) {
        v4f oc = {};
        #pragma unroll
        for (int kc = 0; kc < 2; kc++) {
            v8s pa = *(const v8s*)(sm.ax.Ps + (qt * 16 + l16) * 72 + kc * 32 + quad * 8);
            v8s bfr;
            #pragma unroll
            for (int jj = 0; jj < 8; jj++)
                bfr[jj] = sm.ax.Vs[(kc * 32 + quad * 8 + jj) * 64 + wid * 16 + l16];
            oc = __builtin_amdgcn_mfma_f32_16x16x32_bf16(pa, bfr, oc, 0, 0, 0);
        }
        #pragma unroll
        for (int r = 0; r < 4; r++) {
            int i = qt * 16 + quad * 4 + r;
            if (i >= 1 && i <= 48) {
                int sp = typ == 0 ? 1 + n * 48 + (i - 1) : 1 + (i - 1) * 48 + n;
                attn_b[(rowbase + sp) * DIM + hoff + wid * 16 + l16] =
                    __float2bfloat16(oc[r] * sm.ax.invl[i]);
            }
        }
    }
}

// ---------------- phase: nearby attention (job-strided) ----------------
__device__ __forceinline__ void phase_nearby(SharedU& sm, int tid, int idx,
        const unsigned short* qkvb, const float* colsum, __hip_bfloat16* attn_b) {
    int wid = tid >> 6, lane = tid & 63;
    int quad = lane >> 4, l16 = lane & 15;

    if (idx >= 2304) {
        int b = idx - 2304;
        size_t rb = (size_t)b * SEQ;
        for (int c = tid; c < 512; c += 256) {
            attn_b[(rb + 2304) * DIM + c] =
                __float2bfloat16(colsum[b * 512 + c] * (1.0f / 2305.0f));
            attn_b[rb * DIM + c] =
                __float2bfloat16(bf2f(qkvb[rb * QKVN + 1024 + c]));
        }
        return;
    }

    int bh = idx & 15;
    int tile = idx >> 4;
    int b = bh >> 3, h = bh & 7;
    int t = tile >> 4;
    int sxy = tile & 15;
    int hh0 = (sxy >> 2) * 4, ww0 = (sxy & 3) * 4;
    int nf = (t < 3 ? t : 3) + 1;
    int t0 = t - (nf - 1);
    size_t rowbase = (size_t)b * SEQ;
    int hoff = h * 64;

    auto slot_kp = [&](int slot) -> int {
        int f = slot >> 6, uy = (slot >> 3) & 7, ux = slot & 7;
        int kh = hh0 - 2 + uy, kw = ww0 - 2 + ux;
        int kt = t0 + f;
        bool ok = (kh >= 0) && (kh < 16) && (kw >= 0) && (kw < 16) && (f < nf);
        return ok ? (kt * 256 + kh * 16 + kw + 1) : 0;
    };

    int qp_f = t * 256 + (hh0 + (l16 >> 2)) * 16 + (ww0 + (l16 & 3));
    const unsigned short* qptr = qkvb + (rowbase + qp_f) * QKVN + hoff + quad * 8;
    v8s qa0 = *(const v8s*)qptr;
    v8s qa1 = *(const v8s*)(qptr + 32);

    v8s kb_lo[4], kb_hi[4];
    #pragma unroll
    for (int k = 0; k < 4; k++) {
        int slot = (wid * 4 + k) * 16 + l16;
        int kp = slot_kp(slot);
        const unsigned short* kr = qkvb + (rowbase + kp) * QKVN + hoff + 512;
        kb_lo[k] = *(const v8s*)(kr + quad * 8);
        kb_hi[k] = *(const v8s*)(kr + 32 + quad * 8);
    }

    #pragma unroll
    for (int it = 0; it < 4; it++) {
        int linear = it * 256 + tid;
        int slot = linear >> 3;
        int cd = linear & 7;
        int cs = cd ^ ((slot >> 3) & 7);
        int kp = slot_kp(slot);
        const unsigned short* src = qkvb + (rowbase + kp) * QKVN + hoff + 1024 + cs * 8;
        load_lds16(src, sm.nb.Vs + it * 2048 + wid * 512 + lane * 8);
    }

    v4f st[4];
    #pragma unroll
    for (int k = 0; k < 4; k++) {
        v4f a = {};
        a = __builtin_amdgcn_mfma_f32_16x16x32_bf16(qa0, kb_lo[k], a, 0, 0, 0);
        a = __builtin_amdgcn_mfma_f32_16x16x32_bf16(qa1, kb_hi[k], a, 0, 0, 0);
        st[k] = a;
    }

    const float NEG = -3.0e38f;
    float sv[4][4];
    float pm[4] = {NEG, NEG, NEG, NEG};
    #pragma unroll
    for (int k = 0; k < 4; k++) {
        int slot = (wid * 4 + k) * 16 + l16;
        int f = slot >> 6, uy = (slot >> 3) & 7, ux = slot & 7;
        int kh = hh0 - 2 + uy, kw = ww0 - 2 + ux;
        bool okb = (kh >= 0) && (kh < 16) && (kw >= 0) && (kw < 16) && (f < nf);
        int dyp2 = uy - quad;
        bool oky = okb && (dyp2 >= 0) && (dyp2 <= 4);
        #pragma unroll
        for (int r = 0; r < 4; r++) {
            int dxp2 = ux - r;
            bool ok = oky && (dxp2 >= 0) && (dxp2 <= 4);
            if (f == nf - 1) ok = ok && (dyp2 * 5 + dxp2 < 12);
            float v = ok ? st[k][r] * 0.125f : NEG;
            sv[k][r] = v;
            pm[r] = fmaxf(pm[r], v);
        }
    }
    #pragma unroll
    for (int r = 0; r < 4; r++)
        for (int o = 1; o < 16; o <<= 1) pm[r] = fmaxf(pm[r], __shfl_xor(pm[r], o));
    if (l16 == 0) {
        #pragma unroll
        for (int r = 0; r < 4; r++) sm.nb.redm[(quad * 4 + r) * 4 + wid] = pm[r];
    }
    __syncthreads();   // barrier 1: redm visible, V half-0 staged

    float rm[4];
    #pragma unroll
    for (int r = 0; r < 4; r++) {
        int row = (quad * 4 + r) * 4;
        rm[r] = fmaxf(fmaxf(sm.nb.redm[row], sm.nb.redm[row + 1]),
                      fmaxf(sm.nb.redm[row + 2], sm.nb.redm[row + 3]));
    }

    float ps[4] = {0.f, 0.f, 0.f, 0.f};
    #pragma unroll
    for (int k = 0; k < 4; k++) {
        int slot = (wid * 4 + k) * 16 + l16;
        #pragma unroll
        for (int r = 0; r < 4; r++) {
            float e = __expf(sv[k][r] - rm[r]);
            ps[r] += e;
            sm.nb.Ps[(quad * 4 + r) * 264 + slot] = __bfloat16_as_ushort(__float2bfloat16(e));
        }
    }
    #pragma unroll
    for (int r = 0; r < 4; r++)
        for (int o = 1; o < 16; o <<= 1) ps[r] += __shfl_xor(ps[r], o);
    if (l16 == 0) {
        #pragma unroll
        for (int r = 0; r < 4; r++) sm.nb.reds[(quad * 4 + r) * 4 + wid] = ps[r];
    }
    __syncthreads();   // barrier 2: Ps + reds visible

    float inv[4];
    #pragma unroll
    for (int r = 0; r < 4; r++) {
        int row = (quad * 4 + r) * 4;
        float d = sm.nb.reds[row] + sm.nb.reds[row + 1] + sm.nb.reds[row + 2] + sm.nb.reds[row + 3];
        inv[r] = 1.0f / d;
    }

    int dcol = wid * 16 + l16;
    int c_r = dcol >> 3, d7 = dcol & 7;
    v4f oc = {};
    #pragma unroll
    for (int kc = 0; kc < 4; kc++) {
        v8s pa = *(const v8s*)((const short*)sm.nb.Ps + l16 * 264 + kc * 32 + quad * 8);
        v8s bf;
        #pragma unroll
        for (int j = 0; j < 8; j++) {
            int slot = kc * 32 + quad * 8 + j;
            int key = (slot >> 3) & 7;
            bf[j] = sm.nb.Vs[(slot & 127) * 64 + ((c_r ^ key) * 8) + d7];
        }
        oc = __builtin_amdgcn_mfma_f32_16x16x32_bf16(pa, bf, oc, 0, 0, 0);
    }
    __syncthreads();   // barrier 3: half-0 reads done

    #pragma unroll
    for (int it = 0; it < 4; it++) {
        int linear = 1024 + it * 256 + tid;
        int slot = linear >> 3;
        int cd = linear & 7;
        int cs = cd ^ ((slot >> 3) & 7);
        int kp = slot_kp(slot);
        const unsigned short* src = qkvb + (rowbase + kp) * QKVN + hoff + 1024 + cs * 8;
        load_lds16(src, sm.nb.Vs + it * 2048 + wid * 512 + lane * 8);
    }
    __syncthreads();   // barrier 4: half-1 staged

    #pragma unroll
    for (int kc = 4; kc < 8; kc++) {
        v8s pa = *(const v8s*)((const short*)sm.nb.Ps + l16 * 264 + kc * 32 + quad * 8);
        v8s bf;
        #pragma unroll
        for (int j = 0; j < 8; j++) {
            int slot = kc * 32 + quad * 8 + j;
            int key = (slot >> 3) & 7;
            bf[j] = sm.nb.Vs[(slot & 127) * 64 + ((c_r ^ key) * 8) + d7];
        }
        oc = __builtin_amdgcn_mfma_f32_16x16x32_bf16(pa, bf, oc, 0, 0, 0);
    }

    #pragma unroll
    for (int r = 0; r < 4; r++) {
        int qp = t * 256 + (hh0 + quad) * 16 + (ww0 + r);
        if (qp != 0) {
            attn_b[(rowbase + qp) * DIM + hoff + dcol] =
                __float2bfloat16(oc[r] * inv[r]);
        }
    }
}

// ---------------- the mega-kernel: whole pipeline, one dispatch ----------------
__global__ __launch_bounds__(256, 2) void mega(
    WPack wp, __hip_bfloat16* __restrict__ wqkv, __hip_bfloat16* __restrict__ wo,
    const float4* __restrict__ xin, __hip_bfloat16* __restrict__ xb,
    __hip_bfloat16* __restrict__ attnb, float* __restrict__ colsum,
    __hip_bfloat16* __restrict__ qkvb, float* __restrict__ xout,
    const float* __restrict__ bo0, const float* __restrict__ bo1, const float* __restrict__ bo2,
    int n4, unsigned* bar_cnt, unsigned* bar_gen) {
    __shared__ SharedU sm;
    int tid = threadIdx.x, bid = blockIdx.x;

    phase_prep(sm, tid, bid, wp, wqkv, wo, xin, xb, n4, colsum);
    gsync(bar_cnt, bar_gen);

    for (int l = 0; l < 3; l++) {
        if (bid < 444)
            phase_qkv(sm, tid, bid, xb, wqkv + (size_t)l * QKVN * DIM, qkvb,
                      (l == 2) ? colsum : nullptr);
        gsync(bar_cnt, bar_gen);

        if (l < 2) {
            for (int j = bid; j < 768; j += NBLK) {
                phase_axial(sm, tid, j, (const unsigned short*)qkvb, attnb, l);
                __syncthreads();   // protect Ks/Vs/Ps before next job's staging
            }
        } else {
            for (int j = bid; j < 2306; j += NBLK) {
                phase_nearby(sm, tid, j, (const unsigned short*)qkvb, colsum, attnb);
                __syncthreads();   // protect Vs/Ps before next job's staging
            }
        }
        gsync(bar_cnt, bar_gen);

        const float* bo = (l == 0) ? bo0 : (l == 1) ? bo1 : bo2;
        if (bid < 296) {
            if (l < 2)
                phase_wo(sm, tid, bid, attnb, wo + (size_t)l * DIM * DIM, nullptr, bo, xb, xb);
            else
                phase_wo(sm, tid, bid, attnb, wo + (size_t)l * DIM * DIM, xout, bo, xb, nullptr);
        }
        if (l < 2) gsync(bar_cnt, bar_gen);
    }
}

// ---------------- host launch ----------------
extern "C" void kernel_launch(void* const* d_in, const int* in_sizes, int n_in,
                              void* d_out, int out_size, void* d_ws, size_t ws_size,
                              hipStream_t stream) {
    const float* x = (const float*)d_in[0];
    float* xcur = (float*)d_out;

    char* ws = (char*)d_ws;
    size_t off = 0;
    auto alloc = [&](size_t bytes) -> void* {
        void* p = ws + off;
        off = (off + bytes + 255) & ~(size_t)255;
        return p;
    };
    __hip_bfloat16* wqkv  = (__hip_bfloat16*)alloc((size_t)3 * QKVN * DIM * 2);
    __hip_bfloat16* wo    = (__hip_bfloat16*)alloc((size_t)3 * DIM * DIM * 2);
    __hip_bfloat16* xb    = (__hip_bfloat16*)alloc((size_t)MPAD * DIM * 2);
    __hip_bfloat16* attnb = (__hip_bfloat16*)alloc((size_t)MPAD * DIM * 2);
    float* colsum         = (float*)alloc((size_t)2 * 512 * 4);
    unsigned* bar         = (unsigned*)alloc(256);
    __hip_bfloat16* qkvb  = (__hip_bfloat16*)alloc((size_t)NROWS * QKVN * 2);

    const int n4 = NROWS * DIM / 4;

    WPack wp;
    for (int l = 0; l < 3; l++)
        for (int j = 0; j < 4; j++)
            wp.p[l * 4 + j] = (const float*)d_in[2 + l * 5 + j];

    hipMemsetAsync(bar, 0, 16, stream);   // zero barrier counter + generation

    mega<<<NBLK, 256, 0, stream>>>(
        wp, wqkv, wo, (const float4*)x, xb, attnb, colsum, qkvb, xcur,
        (const float*)d_in[6], (const float*)d_in[11], (const float*)d_in[16],
        n4, bar, bar + 1);
}

// Round 7
// 590.882 us; speedup vs baseline: 4.6781x; 1.5590x over previous
//
#include <hip/hip_runtime.h>
#include <hip/hip_bf16.h>

#define SEQ 2305
#define NROWS 4610      // B*SEQ
#define MPAD 4736       // NROWS rounded up to 128
#define DIM 512
#define QKVN 1536

typedef __attribute__((ext_vector_type(8))) short v8s;
typedef __attribute__((ext_vector_type(4))) float v4f;

__device__ __forceinline__ float bf2f(unsigned short u) {
    return __uint_as_float(((unsigned)u) << 16);
}

__device__ __forceinline__ void load_lds16(const void* g, void* l) {
    __builtin_amdgcn_global_load_lds(
        (const __attribute__((address_space(1))) void*)g,
        (__attribute__((address_space(3))) void*)l, 16, 0, 0);
}

// ---------------- weight transpose + bf16 cast of x + zero colsum ----------------
struct WPack { const float* p[12]; };

__global__ void prep_inputs(WPack wp, __hip_bfloat16* __restrict__ wqkv,
                            __hip_bfloat16* __restrict__ wo,
                            const float4* __restrict__ xin,
                            __hip_bfloat16* __restrict__ xb, int n4,
                            float* __restrict__ colsum) {
    int tx = threadIdx.x, ty = threadIdx.y;
    int m = blockIdx.z;
    if (m == 12) {   // cast x -> xb (bf16), grid-stride; block 0 zeroes colsum
        int tidl = ty * 32 + tx;
        int bid = blockIdx.y * 16 + blockIdx.x;
        if (bid == 0) {
            #pragma unroll
            for (int k = 0; k < 4; k++) colsum[k * 256 + tidl] = 0.f;
        }
        for (int i = bid * 256 + tidl; i < n4; i += 65536) {
            float4 v = xin[i];
            int j = i * 4;
            xb[j + 0] = __float2bfloat16(v.x);
            xb[j + 1] = __float2bfloat16(v.y);
            xb[j + 2] = __float2bfloat16(v.z);
            xb[j + 3] = __float2bfloat16(v.w);
        }
        return;
    }
    __shared__ float tile[32][33];
    const float* src = wp.p[m];
    int l = m >> 2, j = m & 3;
    __hip_bfloat16* dst = (j < 3) ? (wqkv + (size_t)l * QKVN * DIM + (size_t)j * DIM * DIM)
                                  : (wo + (size_t)l * DIM * DIM);
    int bx = blockIdx.x * 32, by = blockIdx.y * 32;
    #pragma unroll
    for (int i = 0; i < 4; i++)
        tile[ty + 8 * i][tx] = src[(size_t)(by + ty + 8 * i) * DIM + bx + tx];
    __syncthreads();
    #pragma unroll
    for (int i = 0; i < 4; i++)
        dst[(size_t)(bx + ty + 8 * i) * DIM + by + tx] = __float2bfloat16(tile[tx][ty + 8 * i]);
}

// ---------------- QKV GEMM: 128x128 tile, BK=64, XCD-chunked bijective swizzle ----------------
// nwg = 37*12 = 444; q=55, r=4 -> XCD k<4 gets 56 blocks, k>=4 gets 55 (m204 bijection).
// wg decoded N-outer (bN = wg/37) so each XCD's chunk keeps ~2 B-panels L2-resident.
__global__ __launch_bounds__(256) void gemm_qkv(
    const __hip_bfloat16* __restrict__ A, const __hip_bfloat16* __restrict__ Bt,
    __hip_bfloat16* __restrict__ Cb, int M, int N, float* __restrict__ colsum) {
    __shared__ short As[2][128 * 32];   // 16 KB (two 32-k sub-buffers)
    __shared__ short Bs[2][128 * 32];   // 16 KB
    const int K = 512;
    int tid = threadIdx.x;
    int wid = tid >> 6, lane = tid & 63;
    int quad = lane >> 4, l16 = lane & 15;

    int orig = blockIdx.x + blockIdx.y * 37;
    int xcd = orig & 7, idx = orig >> 3;
    int wg = (xcd < 4) ? xcd * 56 + idx : 224 + (xcd - 4) * 55 + idx;
    int bM = (wg % 37) * 128, bN = (wg / 37) * 128;
    int wM = (wid >> 1) * 64, wN = (wid & 1) * 64;

    const short* Ag = (const short*)A;
    const short* Bg = (const short*)Bt;

    int rowS = wid * 16 + (lane >> 2);
    int kk8 = (lane & 3) * 8;
    const short* gA = Ag + (size_t)(bM + rowS) * K + kk8;
    const short* gB = Bg + (size_t)(bN + rowS) * K + kk8;

    v4f acc[4][4] = {};
    for (int k0 = 0; k0 < K; k0 += 64) {
        #pragma unroll
        for (int s = 0; s < 2; s++) {
            #pragma unroll
            for (int r = 0; r < 2; r++) {
                load_lds16(gA + k0 + s * 32 + (size_t)r * 64 * K, As[s] + r * 2048 + wid * 512);
                load_lds16(gB + k0 + s * 32 + (size_t)r * 64 * K, Bs[s] + r * 2048 + wid * 512);
            }
        }
        __syncthreads();
        #pragma unroll
        for (int s = 0; s < 2; s++) {
            v8s af[4], bf[4];
            #pragma unroll
            for (int i = 0; i < 4; i++)
                af[i] = *(const v8s*)(As[s] + (wM + i * 16 + l16) * 32 + quad * 8);
            #pragma unroll
            for (int j = 0; j < 4; j++)
                bf[j] = *(const v8s*)(Bs[s] + (wN + j * 16 + l16) * 32 + quad * 8);
            #pragma unroll
            for (int i = 0; i < 4; i++)
                #pragma unroll
                for (int j = 0; j < 4; j++)
                    acc[i][j] = __builtin_amdgcn_mfma_f32_16x16x32_bf16(af[i], bf[j], acc[i][j], 0, 0, 0);
        }
        __syncthreads();
    }

    #pragma unroll
    for (int i = 0; i < 4; i++) {
        int row = bM + wM + i * 16 + quad * 4;
        #pragma unroll
        for (int j = 0; j < 4; j++) {
            int col = bN + wN + j * 16 + l16;
            #pragma unroll
            for (int r = 0; r < 4; r++) {
                int rr = row + r;
                if (rr < M)
                    Cb[(size_t)rr * N + col] = __float2bfloat16(acc[i][j][r]);
            }
        }
    }

    // V-column partial sums (for the all-masked nearby row): cols >= 1024
    if (colsum) {
        #pragma unroll
        for (int j = 0; j < 4; j++) {
            int col = bN + wN + j * 16 + l16;
            if (col >= 1024) {
                float s0 = 0.f, s1 = 0.f;
                #pragma unroll
                for (int i = 0; i < 4; i++) {
                    int row = bM + wM + i * 16 + quad * 4;
                    #pragma unroll
                    for (int r = 0; r < 4; r++) {
                        int rr = row + r;
                        if (rr < M) {
                            float v = acc[i][j][r];
                            if (rr >= SEQ) s1 += v; else s0 += v;
                        }
                    }
                }
                s0 += __shfl_xor(s0, 16); s0 += __shfl_xor(s0, 32);
                s1 += __shfl_xor(s1, 16); s1 += __shfl_xor(s1, 32);
                if (quad == 0) {
                    if (s0 != 0.f) atomicAdd(&colsum[col - 1024], s0);
                    if (s1 != 0.f) atomicAdd(&colsum[512 + col - 1024], s1);
                }
            }
        }
    }
}

// ---------------- Wo GEMM: 64x128 tile, BK=64, XCD-chunked swizzle (nwg=296, q=37, r=0) ----------------
__global__ __launch_bounds__(256) void gemm_lds(
    const __hip_bfloat16* __restrict__ A, const __hip_bfloat16* __restrict__ Bt,
    float* __restrict__ C, const float* __restrict__ bias,
    const __hip_bfloat16* __restrict__ resb, __hip_bfloat16* __restrict__ Cb,
    int M, int N) {
    __shared__ short As[2][64 * 32];    // 8 KB
    __shared__ short Bs[2][128 * 32];   // 16 KB
    const int K = 512;
    int tid = threadIdx.x;
    int wid = tid >> 6, lane = tid & 63;
    int quad = lane >> 4, l16 = lane & 15;

    int orig = blockIdx.x + blockIdx.y * 74;
    int wg = (orig & 7) * 37 + (orig >> 3);
    int bM = (wg % 74) * 64, bN = (wg / 74) * 128;
    int wM = (wid >> 1) * 32, wN = (wid & 1) * 64;

    const short* Ag = (const short*)A;
    const short* Bg = (const short*)Bt;

    int rowS = tid >> 2, cg = tid & 3;
    const short* gA = Ag + (size_t)(bM + rowS) * K + cg * 8;
    const short* gB0 = Bg + (size_t)(bN + rowS) * K + cg * 8;
    const short* gB1 = Bg + (size_t)(bN + 64 + rowS) * K + cg * 8;

    v4f acc[2][4] = {};
    for (int k0 = 0; k0 < K; k0 += 64) {
        #pragma unroll
        for (int s = 0; s < 2; s++) {
            load_lds16(gA + k0 + s * 32, As[s] + wid * 512);
            load_lds16(gB0 + k0 + s * 32, Bs[s] + wid * 512);
            load_lds16(gB1 + k0 + s * 32, Bs[s] + 2048 + wid * 512);
        }
        __syncthreads();
        #pragma unroll
        for (int s = 0; s < 2; s++) {
            v8s af[2], bf[4];
            #pragma unroll
            for (int i = 0; i < 2; i++)
                af[i] = *(const v8s*)(As[s] + (wM + i * 16 + l16) * 32 + quad * 8);
            #pragma unroll
            for (int j = 0; j < 4; j++)
                bf[j] = *(const v8s*)(Bs[s] + (wN + j * 16 + l16) * 32 + quad * 8);
            #pragma unroll
            for (int i = 0; i < 2; i++)
                #pragma unroll
                for (int j = 0; j < 4; j++)
                    acc[i][j] = __builtin_amdgcn_mfma_f32_16x16x32_bf16(af[i], bf[j], acc[i][j], 0, 0, 0);
        }
        __syncthreads();
    }

    const unsigned short* resu = (const unsigned short*)resb;
    #pragma unroll
    for (int i = 0; i < 2; i++) {
        int row = bM + wM + i * 16 + quad * 4;
        #pragma unroll
        for (int j = 0; j < 4; j++) {
            int col = bN + wN + j * 16 + l16;
            #pragma unroll
            for (int r = 0; r < 4; r++) {
                int rr = row + r;
                if (rr < M) {
                    float v = acc[i][j][r];
                    if (bias) v += bias[col];
                    size_t idx = (size_t)rr * N + col;
                    if (resu) v += bf2f(resu[idx]);
                    if (C) C[idx] = v;
                    if (Cb) Cb[idx] = __float2bfloat16(v);
                }
            }
        }
    }
}

// ---------------- axial attention, flash-style MFMA ----------------
__global__ __launch_bounds__(256) void axial_flash(
    const unsigned short* __restrict__ qkvb, __hip_bfloat16* __restrict__ attn_b, int typ) {
    __shared__ short Ks[64 * 64];    // 8 KB, chunk-XOR swizzled
    __shared__ short Vs[64 * 64];    // 8 KB, linear
    __shared__ short Ps[64 * 72];    // 9 KB
    __shared__ float invl[64];

    int tid = threadIdx.x;
    int wid = tid >> 6, lane = tid & 63;
    int quad = lane >> 4, l16 = lane & 15;
    int n = blockIdx.x;
    int b = blockIdx.y >> 3, h = blockIdx.y & 7;
    size_t rowbase = (size_t)b * SEQ;
    int hoff = h * 64;

    #pragma unroll
    for (int it = 0; it < 2; it++) {
        int linear = it * 256 + tid;
        int slot = linear >> 3;
        int cd = linear & 7;
        int cs = cd ^ (slot & 7);
        int sp = (slot == 0) ? 0
               : (slot <= 48 ? (typ == 0 ? 1 + n * 48 + (slot - 1) : 1 + (slot - 1) * 48 + n) : 0);
        const unsigned short* srcK = qkvb + (rowbase + sp) * QKVN + hoff + 512 + cs * 8;
        load_lds16(srcK, Ks + it * 2048 + wid * 512 + lane * 8);
        const unsigned short* srcV = qkvb + (rowbase + sp) * QKVN + hoff + 1024 + cd * 8;
        load_lds16(srcV, Vs + it * 2048 + wid * 512 + lane * 8);
    }

    int qi = wid * 16 + l16;
    int sp_q = (qi >= 1 && qi <= 48)
             ? (typ == 0 ? 1 + n * 48 + (qi - 1) : 1 + (qi - 1) * 48 + n) : 0;
    const unsigned short* qptr = qkvb + (rowbase + sp_q) * QKVN + hoff + quad * 8;
    v8s qa0 = *(const v8s*)qptr;
    v8s qa1 = *(const v8s*)(qptr + 32);

    __syncthreads();

    if (n == 0 && tid < 64) {
        attn_b[rowbase * DIM + hoff + tid] =
            __float2bfloat16(bf2f(qkvb[rowbase * QKVN + hoff + 1024 + tid]));
    }

    v4f st[4];
    #pragma unroll
    for (int kt = 0; kt < 4; kt++) {
        int slot = kt * 16 + l16;
        int s7 = slot & 7;
        v8s blo = *(const v8s*)(Ks + slot * 64 + ((quad ^ s7) * 8));
        v8s bhi = *(const v8s*)(Ks + slot * 64 + (((4 + quad) ^ s7) * 8));
        v4f a = {};
        a = __builtin_amdgcn_mfma_f32_16x16x32_bf16(qa0, blo, a, 0, 0, 0);
        a = __builtin_amdgcn_mfma_f32_16x16x32_bf16(qa1, bhi, a, 0, 0, 0);
        st[kt] = a;
    }

    const float NEG = -3.0e38f;
    float sv[4][4];
    float pm[4] = {NEG, NEG, NEG, NEG};
    #pragma unroll
    for (int kt = 0; kt < 4; kt++) {
        int j = kt * 16 + l16;
        #pragma unroll
        for (int r = 0; r < 4; r++) {
            int i = wid * 16 + quad * 4 + r;
            bool ok = (i >= 1) && (i <= 48) && (j <= i);
            float v = ok ? st[kt][r] * 0.125f : NEG;
            sv[kt][r] = v;
            pm[r] = fmaxf(pm[r], v);
        }
    }
    #pragma unroll
    for (int r = 0; r < 4; r++)
        for (int o = 1; o < 16; o <<= 1) pm[r] = fmaxf(pm[r], __shfl_xor(pm[r], o));

    float ps[4] = {0.f, 0.f, 0.f, 0.f};
    #pragma unroll
    for (int kt = 0; kt < 4; kt++) {
        int j = kt * 16 + l16;
        #pragma unroll
        for (int r = 0; r < 4; r++) {
            float e = __expf(sv[kt][r] - pm[r]);
            ps[r] += e;
            Ps[(wid * 16 + quad * 4 + r) * 72 + j] = (short)__bfloat16_as_ushort(__float2bfloat16(e));
        }
    }
    #pragma unroll
    for (int r = 0; r < 4; r++)
        for (int o = 1; o < 16; o <<= 1) ps[r] += __shfl_xor(ps[r], o);
    if (l16 == 0) {
        #pragma unroll
        for (int r = 0; r < 4; r++)
            invl[wid * 16 + quad * 4 + r] = 1.0f / ps[r];
    }
    __syncthreads();

    #pragma unroll
    for (int qt = 0; qt < 4; qt++) {
        v4f oc = {};
        #pragma unroll
        for (int kc = 0; kc < 2; kc++) {
            v8s pa = *(const v8s*)(Ps + (qt * 16 + l16) * 72 + kc * 32 + quad * 8);
            v8s bfr;
            #pragma unroll
            for (int jj = 0; jj < 8; jj++)
                bfr[jj] = Vs[(kc * 32 + quad * 8 + jj) * 64 + wid * 16 + l16];
            oc = __builtin_amdgcn_mfma_f32_16x16x32_bf16(pa, bfr, oc, 0, 0, 0);
        }
        #pragma unroll
        for (int r = 0; r < 4; r++) {
            int i = qt * 16 + quad * 4 + r;
            if (i >= 1 && i <= 48) {
                int sp = typ == 0 ? 1 + n * 48 + (i - 1) : 1 + (i - 1) * 48 + n;
                attn_b[(rowbase + sp) * DIM + hoff + wid * 16 + l16] =
                    __float2bfloat16(oc[r] * invl[i]);
            }
        }
    }
}

// ---------------- nearby attention: K direct-global gather, V in LDS halves ----------------
__global__ __launch_bounds__(256) void nearby_flash(
    const unsigned short* __restrict__ qkvb, const float* __restrict__ colsum,
    __hip_bfloat16* __restrict__ attn_b) {
    __shared__ short Vs[128 * 64];          // 16 KB, one V half (chunk-XOR key=(slot>>3)&7)
    __shared__ __hip_bfloat16 Ps[16 * 264]; // 8.25 KB
    __shared__ float redm[16 * 4];
    __shared__ float reds[16 * 4];

    int tid = threadIdx.x;
    int wid = tid >> 6, lane = tid & 63;
    int quad = lane >> 4, l16 = lane & 15;

    int idx = blockIdx.x;
    if (idx >= 2304) {      // special rows for one b (from GEMM-accumulated colsum)
        int b = idx - 2304;
        size_t rb = (size_t)b * SEQ;
        for (int c = tid; c < 512; c += 256) {
            attn_b[(rb + 2304) * DIM + c] =
                __float2bfloat16(colsum[b * 512 + c] * (1.0f / 2305.0f));
            attn_b[rb * DIM + c] =
                __float2bfloat16(bf2f(qkvb[rb * QKVN + 1024 + c]));
        }
        return;
    }

    int bh = idx & 15;
    int tile = idx >> 4;
    int b = bh >> 3, h = bh & 7;
    int t = tile >> 4;
    int sxy = tile & 15;
    int hh0 = (sxy >> 2) * 4, ww0 = (sxy & 3) * 4;
    int nf = (t < 3 ? t : 3) + 1;
    int t0 = t - (nf - 1);
    size_t rowbase = (size_t)b * SEQ;
    int hoff = h * 64;

    auto slot_kp = [&](int slot) -> int {
        int f = slot >> 6, uy = (slot >> 3) & 7, ux = slot & 7;
        int kh = hh0 - 2 + uy, kw = ww0 - 2 + ux;
        int kt = t0 + f;
        bool ok = (kh >= 0) && (kh < 16) && (kw >= 0) && (kw < 16) && (f < nf);
        return ok ? (kt * 256 + kh * 16 + kw + 1) : 0;
    };

    int qp_f = t * 256 + (hh0 + (l16 >> 2)) * 16 + (ww0 + (l16 & 3));
    const unsigned short* qptr = qkvb + (rowbase + qp_f) * QKVN + hoff + quad * 8;
    v8s qa0 = *(const v8s*)qptr;
    v8s qa1 = *(const v8s*)(qptr + 32);

    v8s kb_lo[4], kb_hi[4];
    #pragma unroll
    for (int k = 0; k < 4; k++) {
        int slot = (wid * 4 + k) * 16 + l16;
        int kp = slot_kp(slot);
        const unsigned short* kr = qkvb + (rowbase + kp) * QKVN + hoff + 512;
        kb_lo[k] = *(const v8s*)(kr + quad * 8);
        kb_hi[k] = *(const v8s*)(kr + 32 + quad * 8);
    }

    #pragma unroll
    for (int it = 0; it < 4; it++) {
        int linear = it * 256 + tid;
        int slot = linear >> 3;
        int cd = linear & 7;
        int cs = cd ^ ((slot >> 3) & 7);
        int kp = slot_kp(slot);
        const unsigned short* src = qkvb + (rowbase + kp) * QKVN + hoff + 1024 + cs * 8;
        load_lds16(src, Vs + it * 2048 + wid * 512 + lane * 8);
    }

    v4f st[4];
    #pragma unroll
    for (int k = 0; k < 4; k++) {
        v4f a = {};
        a = __builtin_amdgcn_mfma_f32_16x16x32_bf16(qa0, kb_lo[k], a, 0, 0, 0);
        a = __builtin_amdgcn_mfma_f32_16x16x32_bf16(qa1, kb_hi[k], a, 0, 0, 0);
        st[k] = a;
    }

    const float NEG = -3.0e38f;
    float sv[4][4];
    float pm[4] = {NEG, NEG, NEG, NEG};
    #pragma unroll
    for (int k = 0; k < 4; k++) {
        int slot = (wid * 4 + k) * 16 + l16;
        int f = slot >> 6, uy = (slot >> 3) & 7, ux = slot & 7;
        int kh = hh0 - 2 + uy, kw = ww0 - 2 + ux;
        bool okb = (kh >= 0) && (kh < 16) && (kw >= 0) && (kw < 16) && (f < nf);
        int dyp2 = uy - quad;
        bool oky = okb && (dyp2 >= 0) && (dyp2 <= 4);
        #pragma unroll
        for (int r = 0; r < 4; r++) {
            int dxp2 = ux - r;
            bool ok = oky && (dxp2 >= 0) && (dxp2 <= 4);
            if (f == nf - 1) ok = ok && (dyp2 * 5 + dxp2 < 12);
            float v = ok ? st[k][r] * 0.125f : NEG;
            sv[k][r] = v;
            pm[r] = fmaxf(pm[r], v);
        }
    }
    #pragma unroll
    for (int r = 0; r < 4; r++)
        for (int o = 1; o < 16; o <<= 1) pm[r] = fmaxf(pm[r], __shfl_xor(pm[r], o));
    if (l16 == 0) {
        #pragma unroll
        for (int r = 0; r < 4; r++) redm[(quad * 4 + r) * 4 + wid] = pm[r];
    }
    __syncthreads();   // barrier 1: redm visible, V half-0 staged

    float rm[4];
    #pragma unroll
    for (int r = 0; r < 4; r++) {
        int row = (quad * 4 + r) * 4;
        rm[r] = fmaxf(fmaxf(redm[row], redm[row + 1]), fmaxf(redm[row + 2], redm[row + 3]));
    }

    float ps[4] = {0.f, 0.f, 0.f, 0.f};
    #pragma unroll
    for (int k = 0; k < 4; k++) {
        int slot = (wid * 4 + k) * 16 + l16;
        #pragma unroll
        for (int r = 0; r < 4; r++) {
            float e = __expf(sv[k][r] - rm[r]);
            ps[r] += e;
            Ps[(quad * 4 + r) * 264 + slot] = __float2bfloat16(e);
        }
    }
    #pragma unroll
    for (int r = 0; r < 4; r++)
        for (int o = 1; o < 16; o <<= 1) ps[r] += __shfl_xor(ps[r], o);
    if (l16 == 0) {
        #pragma unroll
        for (int r = 0; r < 4; r++) reds[(quad * 4 + r) * 4 + wid] = ps[r];
    }
    __syncthreads();   // barrier 2: Ps + reds visible

    float inv[4];
    #pragma unroll
    for (int r = 0; r < 4; r++) {
        int row = (quad * 4 + r) * 4;
        float d = reds[row] + reds[row + 1] + reds[row + 2] + reds[row + 3];
        inv[r] = 1.0f / d;
    }

    int dcol = wid * 16 + l16;
    int c_r = dcol >> 3, d7 = dcol & 7;
    v4f oc = {};
    #pragma unroll
    for (int kc = 0; kc < 4; kc++) {
        v8s pa = *(const v8s*)((const short*)Ps + l16 * 264 + kc * 32 + quad * 8);
        v8s bf;
        #pragma unroll
        for (int j = 0; j < 8; j++) {
            int slot = kc * 32 + quad * 8 + j;
            int key = (slot >> 3) & 7;
            bf[j] = Vs[(slot & 127) * 64 + ((c_r ^ key) * 8) + d7];
        }
        oc = __builtin_amdgcn_mfma_f32_16x16x32_bf16(pa, bf, oc, 0, 0, 0);
    }
    __syncthreads();   // barrier 3: half-0 reads done

    #pragma unroll
    for (int it = 0; it < 4; it++) {
        int linear = 1024 + it * 256 + tid;
        int slot = linear >> 3;
        int cd = linear & 7;
        int cs = cd ^ ((slot >> 3) & 7);
        int kp = slot_kp(slot);
        const unsigned short* src = qkvb + (rowbase + kp) * QKVN + hoff + 1024 + cs * 8;
        load_lds16(src, Vs + it * 2048 + wid * 512 + lane * 8);
    }
    __syncthreads();   // barrier 4: half-1 staged

    #pragma unroll
    for (int kc = 4; kc < 8; kc++) {
        v8s pa = *(const v8s*)((const short*)Ps + l16 * 264 + kc * 32 + quad * 8);
        v8s bf;
        #pragma unroll
        for (int j = 0; j < 8; j++) {
            int slot = kc * 32 + quad * 8 + j;
            int key = (slot >> 3) & 7;
            bf[j] = Vs[(slot & 127) * 64 + ((c_r ^ key) * 8) + d7];
        }
        oc = __builtin_amdgcn_mfma_f32_16x16x32_bf16(pa, bf, oc, 0, 0, 0);
    }

    #pragma unroll
    for (int r = 0; r < 4; r++) {
        int qp = t * 256 + (hh0 + quad) * 16 + (ww0 + r);
        if (qp != 0) {
            attn_b[(rowbase + qp) * DIM + hoff + dcol] =
                __float2bfloat16(oc[r] * inv[r]);
        }
    }
}

// ---------------- INSTRUMENTATION: hierarchical grid-barrier probe ----------------
// 512 blocks, 2/CU residency (32 KB LDS), 20 two-level barriers, no output writes.
// bar layout (uints): grp_cnt[g] @ g*32, grp_gen[g] @ 256+g*32, root_cnt @ 512, root_gen @ 544.
#define PB_NBLK 512
#define PB_GRPSZ 64
__device__ __forceinline__ void gsync_h(unsigned* bar, unsigned ep, int bid) {
    __syncthreads();
    if (threadIdx.x == 0) {
        __threadfence();   // release (writeback)
        int grp = bid >> 6;   // 8 groups of 64
        unsigned old = __hip_atomic_fetch_add(bar + grp * 32, 1u,
                           __ATOMIC_RELAXED, __HIP_MEMORY_SCOPE_AGENT);
        if (old == ep * PB_GRPSZ - 1) {          // group leader (64th arriver this epoch)
            unsigned o2 = __hip_atomic_fetch_add(bar + 512, 1u,
                              __ATOMIC_RELAXED, __HIP_MEMORY_SCOPE_AGENT);
            if (o2 == ep * 8 - 1) {              // root leader
                __hip_atomic_store(bar + 544, ep, __ATOMIC_RELEASE, __HIP_MEMORY_SCOPE_AGENT);
            } else {
                while (__hip_atomic_load(bar + 544, __ATOMIC_RELAXED, __HIP_MEMORY_SCOPE_AGENT) < ep)
                    __builtin_amdgcn_s_sleep(8);
            }
            __hip_atomic_store(bar + 256 + grp * 32, ep, __ATOMIC_RELEASE, __HIP_MEMORY_SCOPE_AGENT);
        } else {
            while (__hip_atomic_load(bar + 256 + grp * 32, __ATOMIC_RELAXED, __HIP_MEMORY_SCOPE_AGENT) < ep)
                __builtin_amdgcn_s_sleep(32);
        }
        __threadfence();   // acquire (invalidate)
    }
    __syncthreads();
}

__global__ __launch_bounds__(256, 2) void barprobe(unsigned* bar) {
    __shared__ int smdummy[8192];   // 32 KB -> 2 blocks/CU, matching a mega residency
    smdummy[threadIdx.x] = (int)threadIdx.x + (int)blockIdx.x;
    __syncthreads();
    int v = smdummy[255 - (threadIdx.x & 255)];
    asm volatile("" :: "v"(v));     // keep LDS use live (rule 17)
    for (unsigned ep = 1; ep <= 20; ++ep)
        gsync_h(bar, ep, blockIdx.x);
}

// ---------------- host launch ----------------
extern "C" void kernel_launch(void* const* d_in, const int* in_sizes, int n_in,
                              void* d_out, int out_size, void* d_ws, size_t ws_size,
                              hipStream_t stream) {
    const float* x = (const float*)d_in[0];
    float* xcur = (float*)d_out;

    char* ws = (char*)d_ws;
    size_t off = 0;
    auto alloc = [&](size_t bytes) -> void* {
        void* p = ws + off;
        off = (off + bytes + 255) & ~(size_t)255;
        return p;
    };
    __hip_bfloat16* wqkv  = (__hip_bfloat16*)alloc((size_t)3 * QKVN * DIM * 2);
    __hip_bfloat16* wo    = (__hip_bfloat16*)alloc((size_t)3 * DIM * DIM * 2);
    __hip_bfloat16* xb    = (__hip_bfloat16*)alloc((size_t)MPAD * DIM * 2);
    __hip_bfloat16* attnb = (__hip_bfloat16*)alloc((size_t)MPAD * DIM * 2);
    float* colsum         = (float*)alloc((size_t)2 * 512 * 4);
    unsigned* bar         = (unsigned*)alloc(4096);
    __hip_bfloat16* qkvb  = (__hip_bfloat16*)alloc((size_t)NROWS * QKVN * 2);

    const int nElem = NROWS * DIM;
    const int n4 = nElem / 4;

    WPack wp;
    for (int l = 0; l < 3; l++)
        for (int j = 0; j < 4; j++)
            wp.p[l * 4 + j] = (const float*)d_in[2 + l * 5 + j];

    hipMemsetAsync(bar, 0, 4096, stream);   // zero barrier counters/generations

    prep_inputs<<<dim3(16, 16, 13), dim3(32, 8), 0, stream>>>(
        wp, wqkv, wo, (const float4*)x, xb, n4, colsum);

    for (int l = 0; l < 3; l++) {
        gemm_qkv<<<dim3(MPAD / 128, QKVN / 128), 256, 0, stream>>>(
            xb, wqkv + (size_t)l * QKVN * DIM, qkvb,
            NROWS, QKVN, l == 2 ? colsum : nullptr);
        if (l < 2) {
            axial_flash<<<dim3(48, 16), 256, 0, stream>>>((const unsigned short*)qkvb, attnb, l);
        } else {
            nearby_flash<<<2304 + 2, 256, 0, stream>>>(
                (const unsigned short*)qkvb, colsum, attnb);
        }
        const float* bo = (const float*)d_in[6 + l * 5];
        if (l < 2) {
            gemm_lds<<<dim3(MPAD / 64, DIM / 128), 256, 0, stream>>>(
                attnb, wo + (size_t)l * DIM * DIM, nullptr, bo, xb, xb, NROWS, DIM);
        } else {
            gemm_lds<<<dim3(MPAD / 64, DIM / 128), 256, 0, stream>>>(
                attnb, wo + (size_t)l * DIM * DIM, xcur, bo, xb, nullptr, NROWS, DIM);
        }
    }

    // barrier-cost probe: 20 hierarchical grid barriers, no output effect
    barprobe<<<PB_NBLK, 256, 0, stream>>>(bar);
}

// Round 8
// 269.516 us; speedup vs baseline: 10.2561x; 2.1924x over previous
//
#include <hip/hip_runtime.h>
#include <hip/hip_bf16.h>

#define SEQ 2305
#define NROWS 4610      // B*SEQ
#define MPAD 4736       // NROWS rounded up to 128
#define DIM 512
#define QKVN 1536

typedef __attribute__((ext_vector_type(8))) short v8s;
typedef __attribute__((ext_vector_type(4))) float v4f;

__device__ __forceinline__ float bf2f(unsigned short u) {
    return __uint_as_float(((unsigned)u) << 16);
}

__device__ __forceinline__ void load_lds16(const void* g, void* l) {
    __builtin_amdgcn_global_load_lds(
        (const __attribute__((address_space(1))) void*)g,
        (__attribute__((address_space(3))) void*)l, 16, 0, 0);
}

// ---------------- weight transpose + bf16 cast of x + zero colsum ----------------
struct WPack { const float* p[12]; };

__global__ void prep_inputs(WPack wp, __hip_bfloat16* __restrict__ wqkv,
                            __hip_bfloat16* __restrict__ wo,
                            const float4* __restrict__ xin,
                            __hip_bfloat16* __restrict__ xb, int n4,
                            float* __restrict__ colsum) {
    int tx = threadIdx.x, ty = threadIdx.y;
    int m = blockIdx.z;
    if (m == 12) {   // cast x -> xb (bf16), grid-stride; block 0 zeroes colsum
        int tidl = ty * 32 + tx;
        int bid = blockIdx.y * 16 + blockIdx.x;
        if (bid == 0) {
            #pragma unroll
            for (int k = 0; k < 4; k++) colsum[k * 256 + tidl] = 0.f;
        }
        for (int i = bid * 256 + tidl; i < n4; i += 65536) {
            float4 v = xin[i];
            int j = i * 4;
            xb[j + 0] = __float2bfloat16(v.x);
            xb[j + 1] = __float2bfloat16(v.y);
            xb[j + 2] = __float2bfloat16(v.z);
            xb[j + 3] = __float2bfloat16(v.w);
        }
        return;
    }
    __shared__ float tile[32][33];
    const float* src = wp.p[m];
    int l = m >> 2, j = m & 3;
    __hip_bfloat16* dst = (j < 3) ? (wqkv + (size_t)l * QKVN * DIM + (size_t)j * DIM * DIM)
                                  : (wo + (size_t)l * DIM * DIM);
    int bx = blockIdx.x * 32, by = blockIdx.y * 32;
    #pragma unroll
    for (int i = 0; i < 4; i++)
        tile[ty + 8 * i][tx] = src[(size_t)(by + ty + 8 * i) * DIM + bx + tx];
    __syncthreads();
    #pragma unroll
    for (int i = 0; i < 4; i++)
        dst[(size_t)(bx + ty + 8 * i) * DIM + by + tx] = __float2bfloat16(tile[tx][ty + 8 * i]);
}

// ---------------- QKV GEMM: 128x128 tile, BK=32 cross-iteration double buffer ----------------
// 2-phase prefetch (round-2-verified schedule): STAGE(buf^1, chunk it+1); compute buf;
// __syncthreads at bottom (drains prefetch vmcnt + protects buf^1 for overwrite).
// Rationale: 444 blocks = 1.7/CU -- no co-resident blocks to hide the serial drain,
// so issue-ahead matters here (round-2 showed it's neutral at >=4 blocks/CU).
// XCD-chunked bijective swizzle (m204): nwg=444, q=55, r=4.
__global__ __launch_bounds__(256) void gemm_qkv(
    const __hip_bfloat16* __restrict__ A, const __hip_bfloat16* __restrict__ Bt,
    __hip_bfloat16* __restrict__ Cb, int M, int N, float* __restrict__ colsum) {
    __shared__ short As[2][128 * 32];   // 16 KB (double buffer, BK=32)
    __shared__ short Bs[2][128 * 32];   // 16 KB
    const int K = 512;
    int tid = threadIdx.x;
    int wid = tid >> 6, lane = tid & 63;
    int quad = lane >> 4, l16 = lane & 15;

    int orig = blockIdx.x + blockIdx.y * 37;
    int xcd = orig & 7, idx = orig >> 3;
    int wg = (xcd < 4) ? xcd * 56 + idx : 224 + (xcd - 4) * 55 + idx;
    int bM = (wg % 37) * 128, bN = (wg / 37) * 128;
    int wM = (wid >> 1) * 64, wN = (wid & 1) * 64;

    const short* Ag = (const short*)A;
    const short* Bg = (const short*)Bt;

    // staging map (per 128x32 chunk, 4 loads/thread):
    //   load i in {0,1}: row = i*64 + (tid>>2), kk = (tid&3)*8
    //   LDS dest short-idx = i*2048 + wid*512 + lane*8 (wave-linear, rule 21)
    int rowA = tid >> 2;
    int kk8 = (tid & 3) * 8;
    const short* gA = Ag + (size_t)(bM + rowA) * K + kk8;
    const short* gB = Bg + (size_t)(bN + rowA) * K + kk8;

    v4f acc[4][4] = {};

    // prologue: stage chunk 0 into buffer 0
    #pragma unroll
    for (int i = 0; i < 2; i++) {
        load_lds16(gA + (size_t)i * 64 * K, As[0] + i * 2048 + wid * 512);
        load_lds16(gB + (size_t)i * 64 * K, Bs[0] + i * 2048 + wid * 512);
    }
    __syncthreads();   // chunk 0 landed (vmcnt 0 inside)

    #pragma unroll
    for (int it = 0; it < 16; ++it) {
        int b = it & 1;
        if (it < 15) {
            int kn = (it + 1) * 32;
            #pragma unroll
            for (int i = 0; i < 2; i++) {
                load_lds16(gA + kn + (size_t)i * 64 * K, As[b ^ 1] + i * 2048 + wid * 512);
                load_lds16(gB + kn + (size_t)i * 64 * K, Bs[b ^ 1] + i * 2048 + wid * 512);
            }
        }

        v8s af[4], bf[4];
        #pragma unroll
        for (int i = 0; i < 4; i++)
            af[i] = *(const v8s*)(As[b] + (wM + i * 16 + l16) * 32 + quad * 8);
        #pragma unroll
        for (int j = 0; j < 4; j++)
            bf[j] = *(const v8s*)(Bs[b] + (wN + j * 16 + l16) * 32 + quad * 8);
        #pragma unroll
        for (int i = 0; i < 4; i++)
            #pragma unroll
            for (int j = 0; j < 4; j++)
                acc[i][j] = __builtin_amdgcn_mfma_f32_16x16x32_bf16(af[i], bf[j], acc[i][j], 0, 0, 0);

        __syncthreads();   // drain prefetch + protect buf b^1 for overwrite
    }

    #pragma unroll
    for (int i = 0; i < 4; i++) {
        int row = bM + wM + i * 16 + quad * 4;
        #pragma unroll
        for (int j = 0; j < 4; j++) {
            int col = bN + wN + j * 16 + l16;
            #pragma unroll
            for (int r = 0; r < 4; r++) {
                int rr = row + r;
                if (rr < M)
                    Cb[(size_t)rr * N + col] = __float2bfloat16(acc[i][j][r]);
            }
        }
    }

    // V-column partial sums (for the all-masked nearby row): cols >= 1024
    if (colsum) {
        #pragma unroll
        for (int j = 0; j < 4; j++) {
            int col = bN + wN + j * 16 + l16;
            if (col >= 1024) {
                float s0 = 0.f, s1 = 0.f;
                #pragma unroll
                for (int i = 0; i < 4; i++) {
                    int row = bM + wM + i * 16 + quad * 4;
                    #pragma unroll
                    for (int r = 0; r < 4; r++) {
                        int rr = row + r;
                        if (rr < M) {
                            float v = acc[i][j][r];
                            if (rr >= SEQ) s1 += v; else s0 += v;
                        }
                    }
                }
                s0 += __shfl_xor(s0, 16); s0 += __shfl_xor(s0, 32);
                s1 += __shfl_xor(s1, 16); s1 += __shfl_xor(s1, 32);
                if (quad == 0) {
                    if (s0 != 0.f) atomicAdd(&colsum[col - 1024], s0);
                    if (s1 != 0.f) atomicAdd(&colsum[512 + col - 1024], s1);
                }
            }
        }
    }
}

// ---------------- Wo GEMM: 64x128 tile, BK=32 double buffer, 2-phase prefetch ----------------
// Round-2-verified schedule lifted verbatim; XCD swizzle (nwg=296, q=37, r=0).
__global__ __launch_bounds__(256) void gemm_lds(
    const __hip_bfloat16* __restrict__ A, const __hip_bfloat16* __restrict__ Bt,
    float* __restrict__ C, const float* __restrict__ bias,
    const __hip_bfloat16* __restrict__ resb, __hip_bfloat16* __restrict__ Cb,
    int M, int N) {
    __shared__ short As[2][64 * 32];    // 8 KB
    __shared__ short Bs[2][128 * 32];   // 16 KB
    const int K = 512;
    int tid = threadIdx.x;
    int wid = tid >> 6, lane = tid & 63;
    int quad = lane >> 4, l16 = lane & 15;

    int orig = blockIdx.x + blockIdx.y * 74;
    int wg = (orig & 7) * 37 + (orig >> 3);
    int bM = (wg % 74) * 64, bN = (wg / 74) * 128;
    int wM = (wid >> 1) * 32, wN = (wid & 1) * 64;

    const short* Ag = (const short*)A;
    const short* Bg = (const short*)Bt;

    int rowS = tid >> 2, cg = tid & 3;
    const short* gA = Ag + (size_t)(bM + rowS) * K + cg * 8;
    const short* gB0 = Bg + (size_t)(bN + rowS) * K + cg * 8;
    const short* gB1 = Bg + (size_t)(bN + 64 + rowS) * K + cg * 8;

    v4f acc[2][4] = {};

    // prologue: stage chunk 0 into buffer 0 (3 loads/thread)
    load_lds16(gA, As[0] + wid * 512);
    load_lds16(gB0, Bs[0] + wid * 512);
    load_lds16(gB1, Bs[0] + 2048 + wid * 512);
    __syncthreads();

    #pragma unroll
    for (int it = 0; it < 16; ++it) {
        int b = it & 1;
        if (it < 15) {
            int kn = (it + 1) * 32;
            load_lds16(gA + kn, As[b ^ 1] + wid * 512);
            load_lds16(gB0 + kn, Bs[b ^ 1] + wid * 512);
            load_lds16(gB1 + kn, Bs[b ^ 1] + 2048 + wid * 512);
        }

        v8s af[2], bf[4];
        #pragma unroll
        for (int i = 0; i < 2; i++)
            af[i] = *(const v8s*)(As[b] + (wM + i * 16 + l16) * 32 + quad * 8);
        #pragma unroll
        for (int j = 0; j < 4; j++)
            bf[j] = *(const v8s*)(Bs[b] + (wN + j * 16 + l16) * 32 + quad * 8);
        #pragma unroll
        for (int i = 0; i < 2; i++)
            #pragma unroll
            for (int j = 0; j < 4; j++)
                acc[i][j] = __builtin_amdgcn_mfma_f32_16x16x32_bf16(af[i], bf[j], acc[i][j], 0, 0, 0);

        __syncthreads();
    }

    const unsigned short* resu = (const unsigned short*)resb;
    #pragma unroll
    for (int i = 0; i < 2; i++) {
        int row = bM + wM + i * 16 + quad * 4;
        #pragma unroll
        for (int j = 0; j < 4; j++) {
            int col = bN + wN + j * 16 + l16;
            #pragma unroll
            for (int r = 0; r < 4; r++) {
                int rr = row + r;
                if (rr < M) {
                    float v = acc[i][j][r];
                    if (bias) v += bias[col];
                    size_t idx = (size_t)rr * N + col;
                    if (resu) v += bf2f(resu[idx]);
                    if (C) C[idx] = v;
                    if (Cb) Cb[idx] = __float2bfloat16(v);
                }
            }
        }
    }
}

// ---------------- axial attention, flash-style MFMA ----------------
__global__ __launch_bounds__(256) void axial_flash(
    const unsigned short* __restrict__ qkvb, __hip_bfloat16* __restrict__ attn_b, int typ) {
    __shared__ short Ks[64 * 64];    // 8 KB, chunk-XOR swizzled
    __shared__ short Vs[64 * 64];    // 8 KB, linear
    __shared__ short Ps[64 * 72];    // 9 KB
    __shared__ float invl[64];

    int tid = threadIdx.x;
    int wid = tid >> 6, lane = tid & 63;
    int quad = lane >> 4, l16 = lane & 15;
    int n = blockIdx.x;
    int b = blockIdx.y >> 3, h = blockIdx.y & 7;
    size_t rowbase = (size_t)b * SEQ;
    int hoff = h * 64;

    #pragma unroll
    for (int it = 0; it < 2; it++) {
        int linear = it * 256 + tid;
        int slot = linear >> 3;
        int cd = linear & 7;
        int cs = cd ^ (slot & 7);
        int sp = (slot == 0) ? 0
               : (slot <= 48 ? (typ == 0 ? 1 + n * 48 + (slot - 1) : 1 + (slot - 1) * 48 + n) : 0);
        const unsigned short* srcK = qkvb + (rowbase + sp) * QKVN + hoff + 512 + cs * 8;
        load_lds16(srcK, Ks + it * 2048 + wid * 512 + lane * 8);
        const unsigned short* srcV = qkvb + (rowbase + sp) * QKVN + hoff + 1024 + cd * 8;
        load_lds16(srcV, Vs + it * 2048 + wid * 512 + lane * 8);
    }

    int qi = wid * 16 + l16;
    int sp_q = (qi >= 1 && qi <= 48)
             ? (typ == 0 ? 1 + n * 48 + (qi - 1) : 1 + (qi - 1) * 48 + n) : 0;
    const unsigned short* qptr = qkvb + (rowbase + sp_q) * QKVN + hoff + quad * 8;
    v8s qa0 = *(const v8s*)qptr;
    v8s qa1 = *(const v8s*)(qptr + 32);

    __syncthreads();

    if (n == 0 && tid < 64) {
        attn_b[rowbase * DIM + hoff + tid] =
            __float2bfloat16(bf2f(qkvb[rowbase * QKVN + hoff + 1024 + tid]));
    }

    v4f st[4];
    #pragma unroll
    for (int kt = 0; kt < 4; kt++) {
        int slot = kt * 16 + l16;
        int s7 = slot & 7;
        v8s blo = *(const v8s*)(Ks + slot * 64 + ((quad ^ s7) * 8));
        v8s bhi = *(const v8s*)(Ks + slot * 64 + (((4 + quad) ^ s7) * 8));
        v4f a = {};
        a = __builtin_amdgcn_mfma_f32_16x16x32_bf16(qa0, blo, a, 0, 0, 0);
        a = __builtin_amdgcn_mfma_f32_16x16x32_bf16(qa1, bhi, a, 0, 0, 0);
        st[kt] = a;
    }

    const float NEG = -3.0e38f;
    float sv[4][4];
    float pm[4] = {NEG, NEG, NEG, NEG};
    #pragma unroll
    for (int kt = 0; kt < 4; kt++) {
        int j = kt * 16 + l16;
        #pragma unroll
        for (int r = 0; r < 4; r++) {
            int i = wid * 16 + quad * 4 + r;
            bool ok = (i >= 1) && (i <= 48) && (j <= i);
            float v = ok ? st[kt][r] * 0.125f : NEG;
            sv[kt][r] = v;
            pm[r] = fmaxf(pm[r], v);
        }
    }
    #pragma unroll
    for (int r = 0; r < 4; r++)
        for (int o = 1; o < 16; o <<= 1) pm[r] = fmaxf(pm[r], __shfl_xor(pm[r], o));

    float ps[4] = {0.f, 0.f, 0.f, 0.f};
    #pragma unroll
    for (int kt = 0; kt < 4; kt++) {
        int j = kt * 16 + l16;
        #pragma unroll
        for (int r = 0; r < 4; r++) {
            float e = __expf(sv[kt][r] - pm[r]);
            ps[r] += e;
            Ps[(wid * 16 + quad * 4 + r) * 72 + j] = (short)__bfloat16_as_ushort(__float2bfloat16(e));
        }
    }
    #pragma unroll
    for (int r = 0; r < 4; r++)
        for (int o = 1; o < 16; o <<= 1) ps[r] += __shfl_xor(ps[r], o);
    if (l16 == 0) {
        #pragma unroll
        for (int r = 0; r < 4; r++)
            invl[wid * 16 + quad * 4 + r] = 1.0f / ps[r];
    }
    __syncthreads();

    #pragma unroll
    for (int qt = 0; qt < 4; qt++) {
        v4f oc = {};
        #pragma unroll
        for (int kc = 0; kc < 2; kc++) {
            v8s pa = *(const v8s*)(Ps + (qt * 16 + l16) * 72 + kc * 32 + quad * 8);
            v8s bfr;
            #pragma unroll
            for (int jj = 0; jj < 8; jj++)
                bfr[jj] = Vs[(kc * 32 + quad * 8 + jj) * 64 + wid * 16 + l16];
            oc = __builtin_amdgcn_mfma_f32_16x16x32_bf16(pa, bfr, oc, 0, 0, 0);
        }
        #pragma unroll
        for (int r = 0; r < 4; r++) {
            int i = qt * 16 + quad * 4 + r;
            if (i >= 1 && i <= 48) {
                int sp = typ == 0 ? 1 + n * 48 + (i - 1) : 1 + (i - 1) * 48 + n;
                attn_b[(rowbase + sp) * DIM + hoff + wid * 16 + l16] =
                    __float2bfloat16(oc[r] * invl[i]);
            }
        }
    }
}

// ---------------- nearby attention: K direct-global gather, V in LDS halves ----------------
__global__ __launch_bounds__(256) void nearby_flash(
    const unsigned short* __restrict__ qkvb, const float* __restrict__ colsum,
    __hip_bfloat16* __restrict__ attn_b) {
    __shared__ short Vs[128 * 64];          // 16 KB, one V half (chunk-XOR key=(slot>>3)&7)
    __shared__ __hip_bfloat16 Ps[16 * 264]; // 8.25 KB
    __shared__ float redm[16 * 4];
    __shared__ float reds[16 * 4];

    int tid = threadIdx.x;
    int wid = tid >> 6, lane = tid & 63;
    int quad = lane >> 4, l16 = lane & 15;

    int idx = blockIdx.x;
    if (idx >= 2304) {      // special rows for one b (from GEMM-accumulated colsum)
        int b = idx - 2304;
        size_t rb = (size_t)b * SEQ;
        for (int c = tid; c < 512; c += 256) {
            attn_b[(rb + 2304) * DIM + c] =
                __float2bfloat16(colsum[b * 512 + c] * (1.0f / 2305.0f));
            attn_b[rb * DIM + c] =
                __float2bfloat16(bf2f(qkvb[rb * QKVN + 1024 + c]));
        }
        return;
    }

    int bh = idx & 15;
    int tile = idx >> 4;
    int b = bh >> 3, h = bh & 7;
    int t = tile >> 4;
    int sxy = tile & 15;
    int hh0 = (sxy >> 2) * 4, ww0 = (sxy & 3) * 4;
    int nf = (t < 3 ? t : 3) + 1;
    int t0 = t - (nf - 1);
    size_t rowbase = (size_t)b * SEQ;
    int hoff = h * 64;

    auto slot_kp = [&](int slot) -> int {
        int f = slot >> 6, uy = (slot >> 3) & 7, ux = slot & 7;
        int kh = hh0 - 2 + uy, kw = ww0 - 2 + ux;
        int kt = t0 + f;
        bool ok = (kh >= 0) && (kh < 16) && (kw >= 0) && (kw < 16) && (f < nf);
        return ok ? (kt * 256 + kh * 16 + kw + 1) : 0;
    };

    int qp_f = t * 256 + (hh0 + (l16 >> 2)) * 16 + (ww0 + (l16 & 3));
    const unsigned short* qptr = qkvb + (rowbase + qp_f) * QKVN + hoff + quad * 8;
    v8s qa0 = *(const v8s*)qptr;
    v8s qa1 = *(const v8s*)(qptr + 32);

    v8s kb_lo[4], kb_hi[4];
    #pragma unroll
    for (int k = 0; k < 4; k++) {
        int slot = (wid * 4 + k) * 16 + l16;
        int kp = slot_kp(slot);
        const unsigned short* kr = qkvb + (rowbase + kp) * QKVN + hoff + 512;
        kb_lo[k] = *(const v8s*)(kr + quad * 8);
        kb_hi[k] = *(const v8s*)(kr + 32 + quad * 8);
    }

    #pragma unroll
    for (int it = 0; it < 4; it++) {
        int linear = it * 256 + tid;
        int slot = linear >> 3;
        int cd = linear & 7;
        int cs = cd ^ ((slot >> 3) & 7);
        int kp = slot_kp(slot);
        const unsigned short* src = qkvb + (rowbase + kp) * QKVN + hoff + 1024 + cs * 8;
        load_lds16(src, Vs + it * 2048 + wid * 512 + lane * 8);
    }

    v4f st[4];
    #pragma unroll
    for (int k = 0; k < 4; k++) {
        v4f a = {};
        a = __builtin_amdgcn_mfma_f32_16x16x32_bf16(qa0, kb_lo[k], a, 0, 0, 0);
        a = __builtin_amdgcn_mfma_f32_16x16x32_bf16(qa1, kb_hi[k], a, 0, 0, 0);
        st[k] = a;
    }

    const float NEG = -3.0e38f;
    float sv[4][4];
    float pm[4] = {NEG, NEG, NEG, NEG};
    #pragma unroll
    for (int k = 0; k < 4; k++) {
        int slot = (wid * 4 + k) * 16 + l16;
        int f = slot >> 6, uy = (slot >> 3) & 7, ux = slot & 7;
        int kh = hh0 - 2 + uy, kw = ww0 - 2 + ux;
        bool okb = (kh >= 0) && (kh < 16) && (kw >= 0) && (kw < 16) && (f < nf);
        int dyp2 = uy - quad;
        bool oky = okb && (dyp2 >= 0) && (dyp2 <= 4);
        #pragma unroll
        for (int r = 0; r < 4; r++) {
            int dxp2 = ux - r;
            bool ok = oky && (dxp2 >= 0) && (dxp2 <= 4);
            if (f == nf - 1) ok = ok && (dyp2 * 5 + dxp2 < 12);
            float v = ok ? st[k][r] * 0.125f : NEG;
            sv[k][r] = v;
            pm[r] = fmaxf(pm[r], v);
        }
    }
    #pragma unroll
    for (int r = 0; r < 4; r++)
        for (int o = 1; o < 16; o <<= 1) pm[r] = fmaxf(pm[r], __shfl_xor(pm[r], o));
    if (l16 == 0) {
        #pragma unroll
        for (int r = 0; r < 4; r++) redm[(quad * 4 + r) * 4 + wid] = pm[r];
    }
    __syncthreads();   // barrier 1: redm visible, V half-0 staged

    float rm[4];
    #pragma unroll
    for (int r = 0; r < 4; r++) {
        int row = (quad * 4 + r) * 4;
        rm[r] = fmaxf(fmaxf(redm[row], redm[row + 1]), fmaxf(redm[row + 2], redm[row + 3]));
    }

    float ps[4] = {0.f, 0.f, 0.f, 0.f};
    #pragma unroll
    for (int k = 0; k < 4; k++) {
        int slot = (wid * 4 + k) * 16 + l16;
        #pragma unroll
        for (int r = 0; r < 4; r++) {
            float e = __expf(sv[k][r] - rm[r]);
            ps[r] += e;
            Ps[(quad * 4 + r) * 264 + slot] = __float2bfloat16(e);
        }
    }
    #pragma unroll
    for (int r = 0; r < 4; r++)
        for (int o = 1; o < 16; o <<= 1) ps[r] += __shfl_xor(ps[r], o);
    if (l16 == 0) {
        #pragma unroll
        for (int r = 0; r < 4; r++) reds[(quad * 4 + r) * 4 + wid] = ps[r];
    }
    __syncthreads();   // barrier 2: Ps + reds visible

    float inv[4];
    #pragma unroll
    for (int r = 0; r < 4; r++) {
        int row = (quad * 4 + r) * 4;
        float d = reds[row] + reds[row + 1] + reds[row + 2] + reds[row + 3];
        inv[r] = 1.0f / d;
    }

    int dcol = wid * 16 + l16;
    int c_r = dcol >> 3, d7 = dcol & 7;
    v4f oc = {};
    #pragma unroll
    for (int kc = 0; kc < 4; kc++) {
        v8s pa = *(const v8s*)((const short*)Ps + l16 * 264 + kc * 32 + quad * 8);
        v8s bf;
        #pragma unroll
        for (int j = 0; j < 8; j++) {
            int slot = kc * 32 + quad * 8 + j;
            int key = (slot >> 3) & 7;
            bf[j] = Vs[(slot & 127) * 64 + ((c_r ^ key) * 8) + d7];
        }
        oc = __builtin_amdgcn_mfma_f32_16x16x32_bf16(pa, bf, oc, 0, 0, 0);
    }
    __syncthreads();   // barrier 3: half-0 reads done

    #pragma unroll
    for (int it = 0; it < 4; it++) {
        int linear = 1024 + it * 256 + tid;
        int slot = linear >> 3;
        int cd = linear & 7;
        int cs = cd ^ ((slot >> 3) & 7);
        int kp = slot_kp(slot);
        const unsigned short* src = qkvb + (rowbase + kp) * QKVN + hoff + 1024 + cs * 8;
        load_lds16(src, Vs + it * 2048 + wid * 512 + lane * 8);
    }
    __syncthreads();   // barrier 4: half-1 staged

    #pragma unroll
    for (int kc = 4; kc < 8; kc++) {
        v8s pa = *(const v8s*)((const short*)Ps + l16 * 264 + kc * 32 + quad * 8);
        v8s bf;
        #pragma unroll
        for (int j = 0; j < 8; j++) {
            int slot = kc * 32 + quad * 8 + j;
            int key = (slot >> 3) & 7;
            bf[j] = Vs[(slot & 127) * 64 + ((c_r ^ key) * 8) + d7];
        }
        oc = __builtin_amdgcn_mfma_f32_16x16x32_bf16(pa, bf, oc, 0, 0, 0);
    }

    #pragma unroll
    for (int r = 0; r < 4; r++) {
        int qp = t * 256 + (hh0 + quad) * 16 + (ww0 + r);
        if (qp != 0) {
            attn_b[(rowbase + qp) * DIM + hoff + dcol] =
                __float2bfloat16(oc[r] * inv[r]);
        }
    }
}

// ---------------- host launch ----------------
extern "C" void kernel_launch(void* const* d_in, const int* in_sizes, int n_in,
                              void* d_out, int out_size, void* d_ws, size_t ws_size,
                              hipStream_t stream) {
    const float* x = (const float*)d_in[0];
    float* xcur = (float*)d_out;

    char* ws = (char*)d_ws;
    size_t off = 0;
    auto alloc = [&](size_t bytes) -> void* {
        void* p = ws + off;
        off = (off + bytes + 255) & ~(size_t)255;
        return p;
    };
    __hip_bfloat16* wqkv  = (__hip_bfloat16*)alloc((size_t)3 * QKVN * DIM * 2);
    __hip_bfloat16* wo    = (__hip_bfloat16*)alloc((size_t)3 * DIM * DIM * 2);
    __hip_bfloat16* xb    = (__hip_bfloat16*)alloc((size_t)MPAD * DIM * 2);
    __hip_bfloat16* attnb = (__hip_bfloat16*)alloc((size_t)MPAD * DIM * 2);
    float* colsum         = (float*)alloc((size_t)2 * 512 * 4);
    __hip_bfloat16* qkvb  = (__hip_bfloat16*)alloc((size_t)NROWS * QKVN * 2);

    const int nElem = NROWS * DIM;
    const int n4 = nElem / 4;

    WPack wp;
    for (int l = 0; l < 3; l++)
        for (int j = 0; j < 4; j++)
            wp.p[l * 4 + j] = (const float*)d_in[2 + l * 5 + j];
    prep_inputs<<<dim3(16, 16, 13), dim3(32, 8), 0, stream>>>(
        wp, wqkv, wo, (const float4*)x, xb, n4, colsum);

    for (int l = 0; l < 3; l++) {
        gemm_qkv<<<dim3(MPAD / 128, QKVN / 128), 256, 0, stream>>>(
            xb, wqkv + (size_t)l * QKVN * DIM, qkvb,
            NROWS, QKVN, l == 2 ? colsum : nullptr);
        if (l < 2) {
            axial_flash<<<dim3(48, 16), 256, 0, stream>>>((const unsigned short*)qkvb, attnb, l);
        } else {
            nearby_flash<<<2304 + 2, 256, 0, stream>>>(
                (const unsigned short*)qkvb, colsum, attnb);
        }
        const float* bo = (const float*)d_in[6 + l * 5];
        if (l < 2) {
            // residual stream stays bf16: xb <- attnb*Wo + bo + xb (in place)
            gemm_lds<<<dim3(MPAD / 64, DIM / 128), 256, 0, stream>>>(
                attnb, wo + (size_t)l * DIM * DIM, nullptr, bo, xb, xb, NROWS, DIM);
        } else {
            // final layer: write fp32 output
            gemm_lds<<<dim3(MPAD / 64, DIM / 128), 256, 0, stream>>>(
                attnb, wo + (size_t)l * DIM * DIM, xcur, bo, xb, nullptr, NROWS, DIM);
        }
    }
}

// Round 9
// 253.298 us; speedup vs baseline: 10.9128x; 1.0640x over previous
//
#include <hip/hip_runtime.h>
#include <hip/hip_bf16.h>

#define SEQ 2305
#define NROWS 4610      // B*SEQ
#define MPAD 4736       // NROWS rounded up to 128
#define DIM 512
#define QKVN 1536

typedef __attribute__((ext_vector_type(8))) short v8s;
typedef __attribute__((ext_vector_type(4))) float v4f;

__device__ __forceinline__ float bf2f(unsigned short u) {
    return __uint_as_float(((unsigned)u) << 16);
}

__device__ __forceinline__ void load_lds16(const void* g, void* l) {
    __builtin_amdgcn_global_load_lds(
        (const __attribute__((address_space(1))) void*)g,
        (__attribute__((address_space(3))) void*)l, 16, 0, 0);
}

// ---------------- weight transpose + bf16 cast of x + zero colsum ----------------
struct WPack { const float* p[12]; };

__global__ void prep_inputs(WPack wp, __hip_bfloat16* __restrict__ wqkv,
                            __hip_bfloat16* __restrict__ wo,
                            const float4* __restrict__ xin,
                            __hip_bfloat16* __restrict__ xb, int n4,
                            float* __restrict__ colsum) {
    int tx = threadIdx.x, ty = threadIdx.y;
    int m = blockIdx.z;
    if (m == 12) {   // cast x -> xb (bf16), grid-stride; block 0 zeroes colsum
        int tidl = ty * 32 + tx;
        int bid = blockIdx.y * 16 + blockIdx.x;
        if (bid == 0) {
            #pragma unroll
            for (int k = 0; k < 4; k++) colsum[k * 256 + tidl] = 0.f;
        }
        for (int i = bid * 256 + tidl; i < n4; i += 65536) {
            float4 v = xin[i];
            int j = i * 4;
            xb[j + 0] = __float2bfloat16(v.x);
            xb[j + 1] = __float2bfloat16(v.y);
            xb[j + 2] = __float2bfloat16(v.z);
            xb[j + 3] = __float2bfloat16(v.w);
        }
        return;
    }
    __shared__ float tile[32][33];
    const float* src = wp.p[m];
    int l = m >> 2, j = m & 3;
    __hip_bfloat16* dst = (j < 3) ? (wqkv + (size_t)l * QKVN * DIM + (size_t)j * DIM * DIM)
                                  : (wo + (size_t)l * DIM * DIM);
    int bx = blockIdx.x * 32, by = blockIdx.y * 32;
    #pragma unroll
    for (int i = 0; i < 4; i++)
        tile[ty + 8 * i][tx] = src[(size_t)(by + ty + 8 * i) * DIM + bx + tx];
    __syncthreads();
    #pragma unroll
    for (int i = 0; i < 4; i++)
        dst[(size_t)(bx + ty + 8 * i) * DIM + by + tx] = __float2bfloat16(tile[tx][ty + 8 * i]);
}

// ---------------- QKV GEMM: 128x128 tile, BK=64 (twin 32-k sub-buffers), serial schedule ----------------
// Measured-best schedule (r3/r7): stage 8 loads -> sync -> compute both 32-k halves -> sync.
// 2-phase BK=32 prefetch was tried twice (r2 high-occ, r8 low-occ) and regressed both times.
// XCD-chunked bijective swizzle (m204): nwg=444, q=55, r=4; N-outer decode for L2 B-panel reuse.
__global__ __launch_bounds__(256) void gemm_qkv(
    const __hip_bfloat16* __restrict__ A, const __hip_bfloat16* __restrict__ Bt,
    __hip_bfloat16* __restrict__ Cb, int M, int N, float* __restrict__ colsum) {
    __shared__ short As[2][128 * 32];   // 16 KB (two 32-k sub-buffers)
    __shared__ short Bs[2][128 * 32];   // 16 KB
    const int K = 512;
    int tid = threadIdx.x;
    int wid = tid >> 6, lane = tid & 63;
    int quad = lane >> 4, l16 = lane & 15;

    int orig = blockIdx.x + blockIdx.y * 37;
    int xcd = orig & 7, idx = orig >> 3;
    int wg = (xcd < 4) ? xcd * 56 + idx : 224 + (xcd - 4) * 55 + idx;
    int bM = (wg % 37) * 128, bN = (wg / 37) * 128;
    int wM = (wid >> 1) * 64, wN = (wid & 1) * 64;

    const short* Ag = (const short*)A;
    const short* Bg = (const short*)Bt;

    // staging map: round r (0..1), sub-buffer s (0..1):
    //   LDS short idx = r*2048 + wid*512 + lane*8  ->  row = r*64 + wid*16 + (lane>>2), kk = (lane&3)*8
    int rowS = wid * 16 + (lane >> 2);
    int kk8 = (lane & 3) * 8;
    const short* gA = Ag + (size_t)(bM + rowS) * K + kk8;
    const short* gB = Bg + (size_t)(bN + rowS) * K + kk8;

    v4f acc[4][4] = {};
    for (int k0 = 0; k0 < K; k0 += 64) {
        #pragma unroll
        for (int s = 0; s < 2; s++) {
            #pragma unroll
            for (int r = 0; r < 2; r++) {
                load_lds16(gA + k0 + s * 32 + (size_t)r * 64 * K, As[s] + r * 2048 + wid * 512);
                load_lds16(gB + k0 + s * 32 + (size_t)r * 64 * K, Bs[s] + r * 2048 + wid * 512);
            }
        }
        __syncthreads();
        #pragma unroll
        for (int s = 0; s < 2; s++) {
            v8s af[4], bf[4];
            #pragma unroll
            for (int i = 0; i < 4; i++)
                af[i] = *(const v8s*)(As[s] + (wM + i * 16 + l16) * 32 + quad * 8);
            #pragma unroll
            for (int j = 0; j < 4; j++)
                bf[j] = *(const v8s*)(Bs[s] + (wN + j * 16 + l16) * 32 + quad * 8);
            #pragma unroll
            for (int i = 0; i < 4; i++)
                #pragma unroll
                for (int j = 0; j < 4; j++)
                    acc[i][j] = __builtin_amdgcn_mfma_f32_16x16x32_bf16(af[i], bf[j], acc[i][j], 0, 0, 0);
        }
        __syncthreads();
    }

    #pragma unroll
    for (int i = 0; i < 4; i++) {
        int row = bM + wM + i * 16 + quad * 4;
        #pragma unroll
        for (int j = 0; j < 4; j++) {
            int col = bN + wN + j * 16 + l16;
            #pragma unroll
            for (int r = 0; r < 4; r++) {
                int rr = row + r;
                if (rr < M)
                    Cb[(size_t)rr * N + col] = __float2bfloat16(acc[i][j][r]);
            }
        }
    }

    // V-column partial sums (for the all-masked nearby row): cols >= 1024
    if (colsum) {
        #pragma unroll
        for (int j = 0; j < 4; j++) {
            int col = bN + wN + j * 16 + l16;
            if (col >= 1024) {
                float s0 = 0.f, s1 = 0.f;
                #pragma unroll
                for (int i = 0; i < 4; i++) {
                    int row = bM + wM + i * 16 + quad * 4;
                    #pragma unroll
                    for (int r = 0; r < 4; r++) {
                        int rr = row + r;
                        if (rr < M) {
                            float v = acc[i][j][r];
                            if (rr >= SEQ) s1 += v; else s0 += v;
                        }
                    }
                }
                s0 += __shfl_xor(s0, 16); s0 += __shfl_xor(s0, 32);
                s1 += __shfl_xor(s1, 16); s1 += __shfl_xor(s1, 32);
                if (quad == 0) {
                    if (s0 != 0.f) atomicAdd(&colsum[col - 1024], s0);
                    if (s1 != 0.f) atomicAdd(&colsum[512 + col - 1024], s1);
                }
            }
        }
    }
}

// ---------------- Wo GEMM: 64x128 tile, BK=64 (twin 32-k sub-buffers), serial schedule ----------------
// XCD swizzle (nwg=296, q=37, r=0).
__global__ __launch_bounds__(256) void gemm_lds(
    const __hip_bfloat16* __restrict__ A, const __hip_bfloat16* __restrict__ Bt,
    float* __restrict__ C, const float* __restrict__ bias,
    const __hip_bfloat16* __restrict__ resb, __hip_bfloat16* __restrict__ Cb,
    int M, int N) {
    __shared__ short As[2][64 * 32];    // 8 KB
    __shared__ short Bs[2][128 * 32];   // 16 KB
    const int K = 512;
    int tid = threadIdx.x;
    int wid = tid >> 6, lane = tid & 63;
    int quad = lane >> 4, l16 = lane & 15;

    int orig = blockIdx.x + blockIdx.y * 74;
    int wg = (orig & 7) * 37 + (orig >> 3);
    int bM = (wg % 74) * 64, bN = (wg / 74) * 128;
    int wM = (wid >> 1) * 32, wN = (wid & 1) * 64;

    const short* Ag = (const short*)A;
    const short* Bg = (const short*)Bt;

    int rowS = tid >> 2, cg = tid & 3;
    const short* gA = Ag + (size_t)(bM + rowS) * K + cg * 8;
    const short* gB0 = Bg + (size_t)(bN + rowS) * K + cg * 8;
    const short* gB1 = Bg + (size_t)(bN + 64 + rowS) * K + cg * 8;

    v4f acc[2][4] = {};
    for (int k0 = 0; k0 < K; k0 += 64) {
        #pragma unroll
        for (int s = 0; s < 2; s++) {
            load_lds16(gA + k0 + s * 32, As[s] + wid * 512);
            load_lds16(gB0 + k0 + s * 32, Bs[s] + wid * 512);
            load_lds16(gB1 + k0 + s * 32, Bs[s] + 2048 + wid * 512);
        }
        __syncthreads();
        #pragma unroll
        for (int s = 0; s < 2; s++) {
            v8s af[2], bf[4];
            #pragma unroll
            for (int i = 0; i < 2; i++)
                af[i] = *(const v8s*)(As[s] + (wM + i * 16 + l16) * 32 + quad * 8);
            #pragma unroll
            for (int j = 0; j < 4; j++)
                bf[j] = *(const v8s*)(Bs[s] + (wN + j * 16 + l16) * 32 + quad * 8);
            #pragma unroll
            for (int i = 0; i < 2; i++)
                #pragma unroll
                for (int j = 0; j < 4; j++)
                    acc[i][j] = __builtin_amdgcn_mfma_f32_16x16x32_bf16(af[i], bf[j], acc[i][j], 0, 0, 0);
        }
        __syncthreads();
    }

    const unsigned short* resu = (const unsigned short*)resb;
    #pragma unroll
    for (int i = 0; i < 2; i++) {
        int row = bM + wM + i * 16 + quad * 4;
        #pragma unroll
        for (int j = 0; j < 4; j++) {
            int col = bN + wN + j * 16 + l16;
            #pragma unroll
            for (int r = 0; r < 4; r++) {
                int rr = row + r;
                if (rr < M) {
                    float v = acc[i][j][r];
                    if (bias) v += bias[col];
                    size_t idx = (size_t)rr * N + col;
                    if (resu) v += bf2f(resu[idx]);
                    if (C) C[idx] = v;
                    if (Cb) Cb[idx] = __float2bfloat16(v);
                }
            }
        }
    }
}

// ---------------- axial attention, flash-style MFMA ----------------
__global__ __launch_bounds__(256) void axial_flash(
    const unsigned short* __restrict__ qkvb, __hip_bfloat16* __restrict__ attn_b, int typ) {
    __shared__ short Ks[64 * 64];    // 8 KB, chunk-XOR swizzled
    __shared__ short Vs[64 * 64];    // 8 KB, linear
    __shared__ short Ps[64 * 72];    // 9 KB
    __shared__ float invl[64];

    int tid = threadIdx.x;
    int wid = tid >> 6, lane = tid & 63;
    int quad = lane >> 4, l16 = lane & 15;
    int n = blockIdx.x;
    int b = blockIdx.y >> 3, h = blockIdx.y & 7;
    size_t rowbase = (size_t)b * SEQ;
    int hoff = h * 64;

    #pragma unroll
    for (int it = 0; it < 2; it++) {
        int linear = it * 256 + tid;
        int slot = linear >> 3;
        int cd = linear & 7;
        int cs = cd ^ (slot & 7);
        int sp = (slot == 0) ? 0
               : (slot <= 48 ? (typ == 0 ? 1 + n * 48 + (slot - 1) : 1 + (slot - 1) * 48 + n) : 0);
        const unsigned short* srcK = qkvb + (rowbase + sp) * QKVN + hoff + 512 + cs * 8;
        load_lds16(srcK, Ks + it * 2048 + wid * 512 + lane * 8);
        const unsigned short* srcV = qkvb + (rowbase + sp) * QKVN + hoff + 1024 + cd * 8;
        load_lds16(srcV, Vs + it * 2048 + wid * 512 + lane * 8);
    }

    int qi = wid * 16 + l16;
    int sp_q = (qi >= 1 && qi <= 48)
             ? (typ == 0 ? 1 + n * 48 + (qi - 1) : 1 + (qi - 1) * 48 + n) : 0;
    const unsigned short* qptr = qkvb + (rowbase + sp_q) * QKVN + hoff + quad * 8;
    v8s qa0 = *(const v8s*)qptr;
    v8s qa1 = *(const v8s*)(qptr + 32);

    __syncthreads();

    if (n == 0 && tid < 64) {
        attn_b[rowbase * DIM + hoff + tid] =
            __float2bfloat16(bf2f(qkvb[rowbase * QKVN + hoff + 1024 + tid]));
    }

    v4f st[4];
    #pragma unroll
    for (int kt = 0; kt < 4; kt++) {
        int slot = kt * 16 + l16;
        int s7 = slot & 7;
        v8s blo = *(const v8s*)(Ks + slot * 64 + ((quad ^ s7) * 8));
        v8s bhi = *(const v8s*)(Ks + slot * 64 + (((4 + quad) ^ s7) * 8));
        v4f a = {};
        a = __builtin_amdgcn_mfma_f32_16x16x32_bf16(qa0, blo, a, 0, 0, 0);
        a = __builtin_amdgcn_mfma_f32_16x16x32_bf16(qa1, bhi, a, 0, 0, 0);
        st[kt] = a;
    }

    const float NEG = -3.0e38f;
    float sv[4][4];
    float pm[4] = {NEG, NEG, NEG, NEG};
    #pragma unroll
    for (int kt = 0; kt < 4; kt++) {
        int j = kt * 16 + l16;
        #pragma unroll
        for (int r = 0; r < 4; r++) {
            int i = wid * 16 + quad * 4 + r;
            bool ok = (i >= 1) && (i <= 48) && (j <= i);
            float v = ok ? st[kt][r] * 0.125f : NEG;
            sv[kt][r] = v;
            pm[r] = fmaxf(pm[r], v);
        }
    }
    #pragma unroll
    for (int r = 0; r < 4; r++)
        for (int o = 1; o < 16; o <<= 1) pm[r] = fmaxf(pm[r], __shfl_xor(pm[r], o));

    float ps[4] = {0.f, 0.f, 0.f, 0.f};
    #pragma unroll
    for (int kt = 0; kt < 4; kt++) {
        int j = kt * 16 + l16;
        #pragma unroll
        for (int r = 0; r < 4; r++) {
            float e = __expf(sv[kt][r] - pm[r]);
            ps[r] += e;
            Ps[(wid * 16 + quad * 4 + r) * 72 + j] = (short)__bfloat16_as_ushort(__float2bfloat16(e));
        }
    }
    #pragma unroll
    for (int r = 0; r < 4; r++)
        for (int o = 1; o < 16; o <<= 1) ps[r] += __shfl_xor(ps[r], o);
    if (l16 == 0) {
        #pragma unroll
        for (int r = 0; r < 4; r++)
            invl[wid * 16 + quad * 4 + r] = 1.0f / ps[r];
    }
    __syncthreads();

    #pragma unroll
    for (int qt = 0; qt < 4; qt++) {
        v4f oc = {};
        #pragma unroll
        for (int kc = 0; kc < 2; kc++) {
            v8s pa = *(const v8s*)(Ps + (qt * 16 + l16) * 72 + kc * 32 + quad * 8);
            v8s bfr;
            #pragma unroll
            for (int jj = 0; jj < 8; jj++)
                bfr[jj] = Vs[(kc * 32 + quad * 8 + jj) * 64 + wid * 16 + l16];
            oc = __builtin_amdgcn_mfma_f32_16x16x32_bf16(pa, bfr, oc, 0, 0, 0);
        }
        #pragma unroll
        for (int r = 0; r < 4; r++) {
            int i = qt * 16 + quad * 4 + r;
            if (i >= 1 && i <= 48) {
                int sp = typ == 0 ? 1 + n * 48 + (i - 1) : 1 + (i - 1) * 48 + n;
                attn_b[(rowbase + sp) * DIM + hoff + wid * 16 + l16] =
                    __float2bfloat16(oc[r] * invl[i]);
            }
        }
    }
}

// ---------------- nearby attention: K direct-global gather, V in LDS halves ----------------
__global__ __launch_bounds__(256) void nearby_flash(
    const unsigned short* __restrict__ qkvb, const float* __restrict__ colsum,
    __hip_bfloat16* __restrict__ attn_b) {
    __shared__ short Vs[128 * 64];          // 16 KB, one V half (chunk-XOR key=(slot>>3)&7)
    __shared__ __hip_bfloat16 Ps[16 * 264]; // 8.25 KB
    __shared__ float redm[16 * 4];
    __shared__ float reds[16 * 4];

    int tid = threadIdx.x;
    int wid = tid >> 6, lane = tid & 63;
    int quad = lane >> 4, l16 = lane & 15;

    int idx = blockIdx.x;
    if (idx >= 2304) {      // special rows for one b (from GEMM-accumulated colsum)
        int b = idx - 2304;
        size_t rb = (size_t)b * SEQ;
        for (int c = tid; c < 512; c += 256) {
            attn_b[(rb + 2304) * DIM + c] =
                __float2bfloat16(colsum[b * 512 + c] * (1.0f / 2305.0f));
            attn_b[rb * DIM + c] =
                __float2bfloat16(bf2f(qkvb[rb * QKVN + 1024 + c]));
        }
        return;
    }

    int bh = idx & 15;
    int tile = idx >> 4;
    int b = bh >> 3, h = bh & 7;
    int t = tile >> 4;
    int sxy = tile & 15;
    int hh0 = (sxy >> 2) * 4, ww0 = (sxy & 3) * 4;
    int nf = (t < 3 ? t : 3) + 1;
    int t0 = t - (nf - 1);
    size_t rowbase = (size_t)b * SEQ;
    int hoff = h * 64;

    auto slot_kp = [&](int slot) -> int {
        int f = slot >> 6, uy = (slot >> 3) & 7, ux = slot & 7;
        int kh = hh0 - 2 + uy, kw = ww0 - 2 + ux;
        int kt = t0 + f;
        bool ok = (kh >= 0) && (kh < 16) && (kw >= 0) && (kw < 16) && (f < nf);
        return ok ? (kt * 256 + kh * 16 + kw + 1) : 0;
    };

    int qp_f = t * 256 + (hh0 + (l16 >> 2)) * 16 + (ww0 + (l16 & 3));
    const unsigned short* qptr = qkvb + (rowbase + qp_f) * QKVN + hoff + quad * 8;
    v8s qa0 = *(const v8s*)qptr;
    v8s qa1 = *(const v8s*)(qptr + 32);

    v8s kb_lo[4], kb_hi[4];
    #pragma unroll
    for (int k = 0; k < 4; k++) {
        int slot = (wid * 4 + k) * 16 + l16;
        int kp = slot_kp(slot);
        const unsigned short* kr = qkvb + (rowbase + kp) * QKVN + hoff + 512;
        kb_lo[k] = *(const v8s*)(kr + quad * 8);
        kb_hi[k] = *(const v8s*)(kr + 32 + quad * 8);
    }

    #pragma unroll
    for (int it = 0; it < 4; it++) {
        int linear = it * 256 + tid;
        int slot = linear >> 3;
        int cd = linear & 7;
        int cs = cd ^ ((slot >> 3) & 7);
        int kp = slot_kp(slot);
        const unsigned short* src = qkvb + (rowbase + kp) * QKVN + hoff + 1024 + cs * 8;
        load_lds16(src, Vs + it * 2048 + wid * 512 + lane * 8);
    }

    v4f st[4];
    #pragma unroll
    for (int k = 0; k < 4; k++) {
        v4f a = {};
        a = __builtin_amdgcn_mfma_f32_16x16x32_bf16(qa0, kb_lo[k], a, 0, 0, 0);
        a = __builtin_amdgcn_mfma_f32_16x16x32_bf16(qa1, kb_hi[k], a, 0, 0, 0);
        st[k] = a;
    }

    const float NEG = -3.0e38f;
    float sv[4][4];
    float pm[4] = {NEG, NEG, NEG, NEG};
    #pragma unroll
    for (int k = 0; k < 4; k++) {
        int slot = (wid * 4 + k) * 16 + l16;
        int f = slot >> 6, uy = (slot >> 3) & 7, ux = slot & 7;
        int kh = hh0 - 2 + uy, kw = ww0 - 2 + ux;
        bool okb = (kh >= 0) && (kh < 16) && (kw >= 0) && (kw < 16) && (f < nf);
        int dyp2 = uy - quad;
        bool oky = okb && (dyp2 >= 0) && (dyp2 <= 4);
        #pragma unroll
        for (int r = 0; r < 4; r++) {
            int dxp2 = ux - r;
            bool ok = oky && (dxp2 >= 0) && (dxp2 <= 4);
            if (f == nf - 1) ok = ok && (dyp2 * 5 + dxp2 < 12);
            float v = ok ? st[k][r] * 0.125f : NEG;
            sv[k][r] = v;
            pm[r] = fmaxf(pm[r], v);
        }
    }
    #pragma unroll
    for (int r = 0; r < 4; r++)
        for (int o = 1; o < 16; o <<= 1) pm[r] = fmaxf(pm[r], __shfl_xor(pm[r], o));
    if (l16 == 0) {
        #pragma unroll
        for (int r = 0; r < 4; r++) redm[(quad * 4 + r) * 4 + wid] = pm[r];
    }
    __syncthreads();   // barrier 1: redm visible, V half-0 staged

    float rm[4];
    #pragma unroll
    for (int r = 0; r < 4; r++) {
        int row = (quad * 4 + r) * 4;
        rm[r] = fmaxf(fmaxf(redm[row], redm[row + 1]), fmaxf(redm[row + 2], redm[row + 3]));
    }

    float ps[4] = {0.f, 0.f, 0.f, 0.f};
    #pragma unroll
    for (int k = 0; k < 4; k++) {
        int slot = (wid * 4 + k) * 16 + l16;
        #pragma unroll
        for (int r = 0; r < 4; r++) {
            float e = __expf(sv[k][r] - rm[r]);
            ps[r] += e;
            Ps[(quad * 4 + r) * 264 + slot] = __float2bfloat16(e);
        }
    }
    #pragma unroll
    for (int r = 0; r < 4; r++)
        for (int o = 1; o < 16; o <<= 1) ps[r] += __shfl_xor(ps[r], o);
    if (l16 == 0) {
        #pragma unroll
        for (int r = 0; r < 4; r++) reds[(quad * 4 + r) * 4 + wid] = ps[r];
    }
    __syncthreads();   // barrier 2: Ps + reds visible

    float inv[4];
    #pragma unroll
    for (int r = 0; r < 4; r++) {
        int row = (quad * 4 + r) * 4;
        float d = reds[row] + reds[row + 1] + reds[row + 2] + reds[row + 3];
        inv[r] = 1.0f / d;
    }

    int dcol = wid * 16 + l16;
    int c_r = dcol >> 3, d7 = dcol & 7;
    v4f oc = {};
    #pragma unroll
    for (int kc = 0; kc < 4; kc++) {
        v8s pa = *(const v8s*)((const short*)Ps + l16 * 264 + kc * 32 + quad * 8);
        v8s bf;
        #pragma unroll
        for (int j = 0; j < 8; j++) {
            int slot = kc * 32 + quad * 8 + j;
            int key = (slot >> 3) & 7;
            bf[j] = Vs[(slot & 127) * 64 + ((c_r ^ key) * 8) + d7];
        }
        oc = __builtin_amdgcn_mfma_f32_16x16x32_bf16(pa, bf, oc, 0, 0, 0);
    }
    __syncthreads();   // barrier 3: half-0 reads done

    #pragma unroll
    for (int it = 0; it < 4; it++) {
        int linear = 1024 + it * 256 + tid;
        int slot = linear >> 3;
        int cd = linear & 7;
        int cs = cd ^ ((slot >> 3) & 7);
        int kp = slot_kp(slot);
        const unsigned short* src = qkvb + (rowbase + kp) * QKVN + hoff + 1024 + cs * 8;
        load_lds16(src, Vs + it * 2048 + wid * 512 + lane * 8);
    }
    __syncthreads();   // barrier 4: half-1 staged

    #pragma unroll
    for (int kc = 4; kc < 8; kc++) {
        v8s pa = *(const v8s*)((const short*)Ps + l16 * 264 + kc * 32 + quad * 8);
        v8s bf;
        #pragma unroll
        for (int j = 0; j < 8; j++) {
            int slot = kc * 32 + quad * 8 + j;
            int key = (slot >> 3) & 7;
            bf[j] = Vs[(slot & 127) * 64 + ((c_r ^ key) * 8) + d7];
        }
        oc = __builtin_amdgcn_mfma_f32_16x16x32_bf16(pa, bf, oc, 0, 0, 0);
    }

    #pragma unroll
    for (int r = 0; r < 4; r++) {
        int qp = t * 256 + (hh0 + quad) * 16 + (ww0 + r);
        if (qp != 0) {
            attn_b[(rowbase + qp) * DIM + hoff + dcol] =
                __float2bfloat16(oc[r] * inv[r]);
        }
    }
}

// ---------------- host launch ----------------
extern "C" void kernel_launch(void* const* d_in, const int* in_sizes, int n_in,
                              void* d_out, int out_size, void* d_ws, size_t ws_size,
                              hipStream_t stream) {
    const float* x = (const float*)d_in[0];
    float* xcur = (float*)d_out;

    char* ws = (char*)d_ws;
    size_t off = 0;
    auto alloc = [&](size_t bytes) -> void* {
        void* p = ws + off;
        off = (off + bytes + 255) & ~(size_t)255;
        return p;
    };
    __hip_bfloat16* wqkv  = (__hip_bfloat16*)alloc((size_t)3 * QKVN * DIM * 2);
    __hip_bfloat16* wo    = (__hip_bfloat16*)alloc((size_t)3 * DIM * DIM * 2);
    __hip_bfloat16* xb    = (__hip_bfloat16*)alloc((size_t)MPAD * DIM * 2);
    __hip_bfloat16* attnb = (__hip_bfloat16*)alloc((size_t)MPAD * DIM * 2);
    float* colsum         = (float*)alloc((size_t)2 * 512 * 4);
    __hip_bfloat16* qkvb  = (__hip_bfloat16*)alloc((size_t)NROWS * QKVN * 2);

    const int nElem = NROWS * DIM;
    const int n4 = nElem / 4;

    WPack wp;
    for (int l = 0; l < 3; l++)
        for (int j = 0; j < 4; j++)
            wp.p[l * 4 + j] = (const float*)d_in[2 + l * 5 + j];
    prep_inputs<<<dim3(16, 16, 13), dim3(32, 8), 0, stream>>>(
        wp, wqkv, wo, (const float4*)x, xb, n4, colsum);

    for (int l = 0; l < 3; l++) {
        gemm_qkv<<<dim3(MPAD / 128, QKVN / 128), 256, 0, stream>>>(
            xb, wqkv + (size_t)l * QKVN * DIM, qkvb,
            NROWS, QKVN, l == 2 ? colsum : nullptr);
        if (l < 2) {
            axial_flash<<<dim3(48, 16), 256, 0, stream>>>((const unsigned short*)qkvb, attnb, l);
        } else {
            nearby_flash<<<2304 + 2, 256, 0, stream>>>(
                (const unsigned short*)qkvb, colsum, attnb);
        }
        const float* bo = (const float*)d_in[6 + l * 5];
        if (l < 2) {
            // residual stream stays bf16: xb <- attnb*Wo + bo + xb (in place)
            gemm_lds<<<dim3(MPAD / 64, DIM / 128), 256, 0, stream>>>(
                attnb, wo + (size_t)l * DIM * DIM, nullptr, bo, xb, xb, NROWS, DIM);
        } else {
            // final layer: write fp32 output
            gemm_lds<<<dim3(MPAD / 64, DIM / 128), 256, 0, stream>>>(
                attnb, wo + (size_t)l * DIM * DIM, xcur, bo, xb, nullptr, NROWS, DIM);
        }
    }
}